// Round 1
// baseline (19224.446 us; speedup 1.0000x reference)
//
#include <hip/hip_runtime.h>
#include <hip/hip_cooperative_groups.h>
#include <math.h>

namespace cg = cooperative_groups;

// Problem constants
#define B 2048
#define T 128
#define H 512
#define NC 3
#define NO 5
#define G3H 1536
#define BHE ((size_t)B * H)
#define YS ((size_t)B * NO)

typedef _Float16 half8 __attribute__((ext_vector_type(8)));
typedef float float4v __attribute__((ext_vector_type(4)));

#define LO_SCALE 1024.0f
#define INV_LO (1.0f / 1024.0f)
#define F16_MIN_NORM 6.103515625e-05f

__device__ __forceinline__ float sigmoidf_(float x) { return 1.0f / (1.0f + __expf(-x)); }

// Split fp32 -> (hi, lo*1024) f16 pair; hi zeroed in subnormal range (flush safety).
__device__ __forceinline__ void split_f16(float a, _Float16* hi, _Float16* lo) {
    _Float16 h = (_Float16)a;
    if (fabsf(a) < F16_MIN_NORM) h = (_Float16)0.0f;
    *hi = h;
    *lo = (_Float16)((a - (float)h) * LO_SCALE);
}

// element (row,k) of a 512-col matrix stored at row*512 + swzk(row,k):
// 16B chunk c=(k>>3)&7 lives in slot c ^ (row&7)  (LDS-conflict-free fragments)
__device__ __forceinline__ int swzk(int row, int k) {
    return (k & ~63) | ((((k >> 3) & 7) ^ (row & 7)) << 3) | (k & 7);
}
__device__ __forceinline__ size_t hidx(int row, int k) {
    return (size_t)row * H + swzk(row, k);
}

// async 16B global->LDS (wave-uniform LDS base; lane lands at base + lane*16B)
__device__ __forceinline__ void stage16(const _Float16* gp, _Float16* lp) {
    __builtin_amdgcn_global_load_lds(
        (const __attribute__((address_space(1))) unsigned int*)gp,
        (__attribute__((address_space(3))) unsigned int*)lp,
        16, 0, 0);
}

// ---------------- prep kernels (once per launch) ----------------
__global__ void conv3_kernel(const float* __restrict__ w1, const float* __restrict__ w2,
                             const float* __restrict__ w3,
                             _Float16* o1h, _Float16* o1l, _Float16* o2h, _Float16* o2l,
                             _Float16* o3h, _Float16* o3l) {
    int i = blockIdx.x * 256 + threadIdx.x;
    if (i < G3H * H) {
        const int r = i >> 9, k = i & 511;
        const size_t d = (size_t)r * H + swzk(r, k);
        split_f16(w1[i], &o1h[d], &o1l[d]);
        split_f16(w2[i], &o2h[d], &o2l[d]);
        split_f16(w3[i], &o3h[d], &o3l[d]);
    }
}

__global__ void prep_kernel(const float* __restrict__ h01, const float* __restrict__ h02,
                            _Float16* h1h, _Float16* h1l, _Float16* h2h, _Float16* h2l) {
    int i = blockIdx.x * 256 + threadIdx.x;
    if (i < B * H) {
        const int r = i >> 9, k = i & 511;
        const size_t d = (size_t)r * H + swzk(r, k);
        split_f16(h01[i], &h1h[d], &h1l[d]);
        split_f16(h02[i], &h2h[d], &h2l[d]);
    }
}

// ---------------- staging: one 64x64 K-tile (A 16KB + 3-gate W 48KB) ----------------
// 512 threads: A = 512 chunks (1/thread/component), W = 1536 chunks (3/thread/comp)
__device__ __forceinline__ void stage_tile(
    const _Float16* __restrict__ Ahp, const _Float16* __restrict__ Alp,
    const _Float16* __restrict__ Whp, const _Float16* __restrict__ Wlp,
    int m0, int n0, int k0, int tid, int wv,
    _Float16* sAh, _Float16* sAl, _Float16* sWh, _Float16* sWl)
{
    {
        const int row = tid >> 3, kc = tid & 7;
        const size_t off = (size_t)(m0 + row) * H + k0 + kc * 8;
        stage16(Ahp + off, &sAh[(wv * 64) * 8]);
        stage16(Alp + off, &sAl[(wv * 64) * 8]);
    }
    #pragma unroll
    for (int j = 0; j < 3; ++j) {
        const int cid = j * 512 + tid;
        const int gg = cid >> 9, rem = cid & 511;
        const int nr = rem >> 3, kc = rem & 7;
        const size_t off = (size_t)(gg * H + n0 + nr) * H + k0 + kc * 8;
        stage16(Whp + off, &sWh[(j * 512 + wv * 64) * 8]);
        stage16(Wlp + off, &sWl[(j * 512 + wv * 64) * 8]);
    }
}

// ---------------- old 4-set compute tile (fallback kernels) ----------------
__device__ __forceinline__ void compute_tile(
    const _Float16* sAh, const _Float16* sAl,
    const _Float16* sWh, const _Float16* sWl,
    int wm, int wn, int ln, int qd, int sN,
    float4v (&accH)[4][2], float4v (&accL)[4][2])
{
    #pragma unroll
    for (int ks = 0; ks < 2; ++ks) {
        const int c = ks * 4 + qd;
        const int row = wm * 16 + ln;
        const int ai = row * 64 + ((c ^ (row & 7)) << 3);
        half8 afh = *(const half8*)&sAh[ai];
        half8 afl = *(const half8*)&sAl[ai];
        #pragma unroll
        for (int g = 0; g < 3; ++g) {
            const int s = (g < 2) ? g : sN;
            #pragma unroll
            for (int nt = 0; nt < 2; ++nt) {
                const int nr = wn * 32 + nt * 16 + ln;
                const int wi = (g * 64 + nr) * 64 + ((c ^ (nr & 7)) << 3);
                half8 bh = *(const half8*)&sWh[wi];
                half8 bl = *(const half8*)&sWl[wi];
                accH[s][nt] = __builtin_amdgcn_mfma_f32_16x16x32_f16(afh, bh, accH[s][nt], 0, 0, 0);
                accL[s][nt] = __builtin_amdgcn_mfma_f32_16x16x32_f16(afh, bl, accL[s][nt], 0, 0, 0);
                accL[s][nt] = __builtin_amdgcn_mfma_f32_16x16x32_f16(afl, bh, accL[s][nt], 0, 0, 0);
            }
        }
    }
}

// ---------------- new 6-set compute tile, (wm,wn)=(2,4) remap ----------------
// wave covers 32 rows x 16 cols x 3 gates. LDS reads/tile/wave: 20 (was 28).
// SB = accumulator set base (0 for gh1/gi2, 3 for gh2) -- compile-time (rule #20).
template <int SB>
__device__ __forceinline__ void compute_tile6(
    const _Float16* sAh_, const _Float16* sAl_,
    const _Float16* sWh_, const _Float16* sWl_,
    int wm, int wn, int ln, int qd,
    float4v (&accH)[6][2], float4v (&accL)[6][2])
{
    #pragma unroll
    for (int ks = 0; ks < 2; ++ks) {
        const int c = ks * 4 + qd;
        half8 afh[2], afl[2];
        #pragma unroll
        for (int ms = 0; ms < 2; ++ms) {
            const int row = wm * 32 + ms * 16 + ln;
            const int ai = row * 64 + ((c ^ (row & 7)) << 3);
            afh[ms] = *(const half8*)&sAh_[ai];
            afl[ms] = *(const half8*)&sAl_[ai];
        }
        #pragma unroll
        for (int g = 0; g < 3; ++g) {
            const int nr = wn * 16 + ln;
            const int wi = (g * 64 + nr) * 64 + ((c ^ (nr & 7)) << 3);
            half8 bh = *(const half8*)&sWh_[wi];
            half8 bl = *(const half8*)&sWl_[wi];
            #pragma unroll
            for (int ms = 0; ms < 2; ++ms) {
                accH[SB + g][ms] = __builtin_amdgcn_mfma_f32_16x16x32_f16(afh[ms], bh, accH[SB + g][ms], 0, 0, 0);
                accL[SB + g][ms] = __builtin_amdgcn_mfma_f32_16x16x32_f16(afh[ms], bl, accL[SB + g][ms], 0, 0, 0);
                accL[SB + g][ms] = __builtin_amdgcn_mfma_f32_16x16x32_f16(afl[ms], bh, accL[SB + g][ms], 0, 0, 0);
            }
        }
    }
}

// ---------------- persistent cooperative kernel (all T steps) ----------------
struct RP {
    const float* cmds; const float* y0;
    const float* W_ih1; const float* b_ih1; const float* b_hh1;
    const float* b_ih2; const float* b_hh2;
    const float* Wout; const float* bout;
    const _Float16* wh1h; const _Float16* wh1l;
    const _Float16* wi2h; const _Float16* wi2l;
    const _Float16* wh2h; const _Float16* wh2l;
    _Float16* h1h; _Float16* h1l;   // 2 contiguous slots each
    _Float16* h2h; _Float16* h2l;
    float* ybuf;                    // 2 contiguous slots of B*NO
    float* out;
};

__global__ __launch_bounds__(512, 1) void rnn_persistent(RP p) {
    cg::grid_group grid = cg::this_grid();

    __shared__ _Float16 sAh[2][4096], sAl[2][4096];     // 32 KB
    __shared__ _Float16 sWh[2][12288], sWl[2][12288];   // 96 KB
    __shared__ float sX[64 * 8];
    __shared__ float sWi1[3][8][64];
    __shared__ float sBi1[3][64], sBh1[3][64], sBi2[3][64], sBh2[3][64];
    __shared__ float sWo[NO][64];

    const int tid = threadIdx.x;
    const int wv = tid >> 6, lane = tid & 63;
    const int wm = wv >> 2, wn = wv & 3;                 // (2,4) remap
    const int ln = lane & 15, qd = lane >> 4;
    const int n0 = (blockIdx.x & 7) * 64;                // XCD-local W slice
    const int m0 = (blockIdx.x >> 3) * 64;

    // one-time LDS fills (first K-loop __syncthreads publishes them)
    for (int i = tid; i < 3 * 64 * 8; i += 512) {
        const int g = i >> 9, rem = i & 511, n = rem >> 3, k = rem & 7;
        sWi1[g][k][n] = p.W_ih1[(g * H + n0 + n) * 8 + k];
    }
    if (tid < 192) {
        const int g = tid >> 6, n = tid & 63;
        sBi1[g][n] = p.b_ih1[g * H + n0 + n];
        sBh1[g][n] = p.b_hh1[g * H + n0 + n];
        sBi2[g][n] = p.b_ih2[g * H + n0 + n];
        sBh2[g][n] = p.b_hh2[g * H + n0 + n];
    }
    if (tid < NO * 64)
        sWo[tid >> 6][tid & 63] = p.Wout[(size_t)(tid >> 6) * H + n0 + (tid & 63)];

    // stage phase-1 tile 0 for t=0 (h1 slot 0, W_hh1)
    stage_tile(p.h1h, p.h1l, p.wh1h, p.wh1l, m0, n0, 0, tid, wv,
               sAh[0], sAl[0], sWh[0], sWl[0]);

    float4v accH[6][2], accL[6][2];
    const int gnl = wn * 16 + ln;
    const int gn = n0 + gnl;

    for (int t = 0; t < T; ++t) {
        const int si = t & 1;
        const size_t op = (size_t)si * BHE, on = (size_t)(si ^ 1) * BHE;
        const _Float16* h1ph = p.h1h + op; const _Float16* h1pl = p.h1l + op;
        _Float16* h1nh = p.h1h + on;       _Float16* h1nl = p.h1l + on;
        const _Float16* h2ph = p.h2h + op; const _Float16* h2pl = p.h2l + op;
        _Float16* h2nh = p.h2h + on;       _Float16* h2nl = p.h2l + on;
        float* ybufI = p.ybuf + (size_t)si * YS;         // y[t] accumulates here
        const float* ybufC = p.ybuf + (size_t)(si ^ 1) * YS; // y[t-1] consumed here

        // ---- phase-1 prologue: sX = [y_{t-1}, cmd_t]; out[t-1]; bias-init ybuf[si] ----
        if (t == 0) {
            if (tid < 64) {
                #pragma unroll
                for (int o2 = 0; o2 < NO; ++o2)
                    sX[tid * 8 + o2] = p.y0[(size_t)(m0 + tid) * NO + o2];
            }
        } else if (tid < 64) {
            const float* yr = ybufC + (size_t)(m0 + tid) * NO;
            #pragma unroll
            for (int o2 = 0; o2 < NO; ++o2) {
                const float v = yr[o2];
                sX[tid * 8 + o2] = v;
                if (n0 == 0)
                    p.out[(size_t)(m0 + tid) * (T * NO) + (size_t)(t - 1) * NO + o2] = v;
            }
        }
        if (tid < 64) {
            #pragma unroll
            for (int c = 0; c < NC; ++c)
                sX[tid * 8 + NO + c] =
                    p.cmds[(size_t)t * B * NC + (size_t)(m0 + tid) * NC + c];
        }
        if (n0 == 0 && tid >= 128 && tid < 128 + 64 * NO) {
            const int i = tid - 128;
            ybufI[(size_t)(m0 + i / NO) * NO + (i % NO)] = p.bout[i % NO];
        }

        #pragma unroll
        for (int s = 0; s < 6; ++s)
            #pragma unroll
            for (int ms = 0; ms < 2; ++ms) { accH[s][ms] = (float4v)(0.f); accL[s][ms] = (float4v)(0.f); }

        // ---- phase-1 K-loop: tiles 0-7 gh1 (sets 0-2), 8-15 gh2 (sets 3-5) ----
        for (int it = 0; it < 16; ++it) {
            const int buf = it & 1;
            __syncthreads();
            if (it + 1 < 16) {
                const int k0 = ((it + 1) & 7) * 64;
                if (it + 1 < 8)
                    stage_tile(h1ph, h1pl, p.wh1h, p.wh1l, m0, n0, k0, tid, wv,
                               sAh[buf ^ 1], sAl[buf ^ 1], sWh[buf ^ 1], sWl[buf ^ 1]);
                else
                    stage_tile(h2ph, h2pl, p.wh2h, p.wh2l, m0, n0, k0, tid, wv,
                               sAh[buf ^ 1], sAl[buf ^ 1], sWh[buf ^ 1], sWl[buf ^ 1]);
            }
            if (it < 8)
                compute_tile6<0>(sAh[buf], sAl[buf], sWh[buf], sWl[buf], wm, wn, ln, qd, accH, accL);
            else
                compute_tile6<3>(sAh[buf], sAl[buf], sWh[buf], sWl[buf], wm, wn, ln, qd, accH, accL);
        }

        // ---- epilogue 1: h1[t] = GRU(x, h1[t-1]) ----
        #pragma unroll
        for (int ms = 0; ms < 2; ++ms) {
            #pragma unroll
            for (int r = 0; r < 4; ++r) {
                const int mloc = wm * 32 + ms * 16 + qd * 4 + r;
                const int m = m0 + mloc;
                float giR = sBi1[0][gnl], giZ = sBi1[1][gnl], giN = sBi1[2][gnl];
                #pragma unroll
                for (int k = 0; k < 8; ++k) {
                    const float xv = sX[mloc * 8 + k];
                    giR = fmaf(xv, sWi1[0][k][gnl], giR);
                    giZ = fmaf(xv, sWi1[1][k][gnl], giZ);
                    giN = fmaf(xv, sWi1[2][k][gnl], giN);
                }
                const float gR = giR + sBh1[0][gnl] + accH[0][ms][r] + accL[0][ms][r] * INV_LO;
                const float gZ = giZ + sBh1[1][gnl] + accH[1][ms][r] + accL[1][ms][r] * INV_LO;
                const float gNh = sBh1[2][gnl] + accH[2][ms][r] + accL[2][ms][r] * INV_LO;
                const float R = sigmoidf_(gR), Z = sigmoidf_(gZ);
                const float N = tanhf(fmaf(R, gNh, giN));
                const size_t idx = hidx(m, gn);
                const float hp = (float)h1ph[idx] + (float)h1pl[idx] * INV_LO;
                const float hv = (1.f - Z) * N + Z * hp;
                split_f16(hv, &h1nh[idx], &h1nl[idx]);
            }
        }

        grid.sync();

        // ---- phase 2: gi2 = h1[t] @ W_ih2^T (sets 0-2 reused; gh2 lives in 3-5) ----
        stage_tile(h1nh, h1nl, p.wi2h, p.wi2l, m0, n0, 0, tid, wv,
                   sAh[0], sAl[0], sWh[0], sWl[0]);
        #pragma unroll
        for (int s = 0; s < 3; ++s)
            #pragma unroll
            for (int ms = 0; ms < 2; ++ms) { accH[s][ms] = (float4v)(0.f); accL[s][ms] = (float4v)(0.f); }

        for (int it = 0; it < 8; ++it) {
            const int buf = it & 1;
            __syncthreads();
            if (it + 1 < 8)
                stage_tile(h1nh, h1nl, p.wi2h, p.wi2l, m0, n0, (it + 1) * 64, tid, wv,
                           sAh[buf ^ 1], sAl[buf ^ 1], sWh[buf ^ 1], sWl[buf ^ 1]);
            else if (t + 1 < T)  // prefetch next phase-1 tile 0 (h1[t] stable since sync) -> buf0
                stage_tile(h1nh, h1nl, p.wh1h, p.wh1l, m0, n0, 0, tid, wv,
                           sAh[0], sAl[0], sWh[0], sWl[0]);
            compute_tile6<0>(sAh[buf], sAl[buf], sWh[buf], sWl[buf], wm, wn, ln, qd, accH, accL);
        }

        // ---- epilogue 2: h2[t] + y[t] partials (shfl over 16 n-cols, then atomics) ----
        #pragma unroll
        for (int ms = 0; ms < 2; ++ms) {
            #pragma unroll
            for (int r = 0; r < 4; ++r) {
                const int mloc = wm * 32 + ms * 16 + qd * 4 + r;
                const int m = m0 + mloc;
                const float gR = sBi2[0][gnl] + accH[0][ms][r] + accL[0][ms][r] * INV_LO
                               + sBh2[0][gnl] + accH[3][ms][r] + accL[3][ms][r] * INV_LO;
                const float gZ = sBi2[1][gnl] + accH[1][ms][r] + accL[1][ms][r] * INV_LO
                               + sBh2[1][gnl] + accH[4][ms][r] + accL[4][ms][r] * INV_LO;
                const float gNi = sBi2[2][gnl] + accH[2][ms][r] + accL[2][ms][r] * INV_LO;
                const float gNh = sBh2[2][gnl] + accH[5][ms][r] + accL[5][ms][r] * INV_LO;
                const float R = sigmoidf_(gR), Z = sigmoidf_(gZ);
                const float N = tanhf(fmaf(R, gNh, gNi));
                const size_t idx = hidx(m, gn);
                const float hp = (float)h2ph[idx] + (float)h2pl[idx] * INV_LO;
                const float hv = (1.f - Z) * N + Z * hp;
                split_f16(hv, &h2nh[idx], &h2nl[idx]);

                float p0 = hv * sWo[0][gnl];
                float p1 = hv * sWo[1][gnl];
                float p2 = hv * sWo[2][gnl];
                float p3 = hv * sWo[3][gnl];
                float p4 = hv * sWo[4][gnl];
                #pragma unroll
                for (int off = 1; off < 16; off <<= 1) {
                    p0 += __shfl_xor(p0, off, 64);
                    p1 += __shfl_xor(p1, off, 64);
                    p2 += __shfl_xor(p2, off, 64);
                    p3 += __shfl_xor(p3, off, 64);
                    p4 += __shfl_xor(p4, off, 64);
                }
                if (ln == 0) {
                    float* yp = ybufI + (size_t)m * NO;
                    atomicAdd(yp + 0, p0);
                    atomicAdd(yp + 1, p1);
                    atomicAdd(yp + 2, p2);
                    atomicAdd(yp + 3, p3);
                    atomicAdd(yp + 4, p4);
                }
            }
        }

        grid.sync();
    }

    // final y_{T-1}: slot (T-1)&1 = 1
    if (n0 == 0 && tid < 64 * NO) {
        const int r = tid / NO, o2 = tid % NO;
        p.out[(size_t)(m0 + r) * (T * NO) + (size_t)(T - 1) * NO + o2] =
            p.ybuf[YS + (size_t)(m0 + r) * NO + o2];
    }
}

// ================= fallback path: original per-timestep kernels =================
__global__ __launch_bounds__(512, 1) void gru1_kernel(
    const _Float16* __restrict__ Ah, const _Float16* __restrict__ Al,
    const _Float16* __restrict__ Wh, const _Float16* __restrict__ Wl,
    const _Float16* __restrict__ h2ph, const _Float16* __restrict__ h2pl,
    const float* __restrict__ Wout, const float* __restrict__ bout,
    const float* __restrict__ y0, const float* __restrict__ cmd_t,
    const float* __restrict__ W_ih1,
    const float* __restrict__ b_ih1, const float* __restrict__ b_hh1,
    _Float16* __restrict__ hnh, _Float16* __restrict__ hnl,
    float* __restrict__ out, int t)
{
    __shared__ _Float16 sAh[2][4096], sAl[2][4096];
    __shared__ _Float16 sWh[2][12288], sWl[2][12288];
    __shared__ float sX[64 * 8];
    __shared__ float sWi1[3][8][64];
    __shared__ float sBi1[3][64], sBh1[3][64];

    const int tid = threadIdx.x;
    const int wv = tid >> 6, lane = tid & 63;
    const int wm = wv >> 1, wn = wv & 1;
    const int ln = lane & 15, qd = lane >> 4;
    const int n0 = (blockIdx.x & 7) * 64;
    const int m0 = (blockIdx.x >> 3) * 64;

    for (int i = tid; i < 3 * 64 * 8; i += 512) {
        const int g = i >> 9, rem = i & 511, n = rem >> 3, k = rem & 7;
        sWi1[g][k][n] = W_ih1[(g * H + n0 + n) * 8 + k];
    }
    if (tid < 192) {
        const int g = tid >> 6, n = tid & 63;
        sBi1[g][n] = b_ih1[g * H + n0 + n];
        sBh1[g][n] = b_hh1[g * H + n0 + n];
    }

    float4v accH[4][2], accL[4][2];
    #pragma unroll
    for (int s = 0; s < 4; ++s)
        #pragma unroll
        for (int nt = 0; nt < 2; ++nt) { accH[s][nt] = (float4v)(0.f); accL[s][nt] = (float4v)(0.f); }

    stage_tile(Ah, Al, Wh, Wl, m0, n0, 0, tid, wv, sAh[0], sAl[0], sWh[0], sWl[0]);

    const int yr = tid >> 3, yp = tid & 7;
    if (t == 0) {
        if (tid < 64) {
            #pragma unroll
            for (int o2 = 0; o2 < NO; ++o2)
                sX[tid * 8 + o2] = y0[(size_t)(m0 + tid) * NO + o2];
        }
    } else {
        const int row = m0 + yr;
        float a5[NO] = {0.f, 0.f, 0.f, 0.f, 0.f};
        #pragma unroll
        for (int s = 0; s < 8; ++s) {
            const size_t base = (size_t)row * H + yp * 64 + s * 8;
            half8 hh8 = *(const half8*)(h2ph + base);
            half8 hl8 = *(const half8*)(h2pl + base);
            const int kb = yp * 64 + ((s ^ (row & 7)) << 3);
            #pragma unroll
            for (int j4 = 0; j4 < 2; ++j4) {
                float4 wv4[NO];
                #pragma unroll
                for (int o2 = 0; o2 < NO; ++o2)
                    wv4[o2] = *(const float4*)(Wout + (size_t)o2 * H + kb + j4 * 4);
                #pragma unroll
                for (int jj = 0; jj < 4; ++jj) {
                    const int j = j4 * 4 + jj;
                    const float hv = (float)hh8[j] + (float)hl8[j] * INV_LO;
                    a5[0] = fmaf(hv, ((const float*)&wv4[0])[jj], a5[0]);
                    a5[1] = fmaf(hv, ((const float*)&wv4[1])[jj], a5[1]);
                    a5[2] = fmaf(hv, ((const float*)&wv4[2])[jj], a5[2]);
                    a5[3] = fmaf(hv, ((const float*)&wv4[3])[jj], a5[3]);
                    a5[4] = fmaf(hv, ((const float*)&wv4[4])[jj], a5[4]);
                }
            }
        }
        #pragma unroll
        for (int off = 1; off < 8; off <<= 1)
            #pragma unroll
            for (int o2 = 0; o2 < NO; ++o2) a5[o2] += __shfl_xor(a5[o2], off, 64);
        if (yp == 0) {
            #pragma unroll
            for (int o2 = 0; o2 < NO; ++o2) {
                const float y = a5[o2] + bout[o2];
                sX[yr * 8 + o2] = y;
                if (n0 == 0)
                    out[(size_t)(m0 + yr) * (T * NO) + (size_t)(t - 1) * NO + o2] = y;
            }
        }
    }
    if (tid < 64) {
        #pragma unroll
        for (int c = 0; c < NC; ++c)
            sX[tid * 8 + NO + c] = cmd_t[(size_t)(m0 + tid) * NC + c];
    }

    for (int it = 0; it < 8; ++it) {
        const int buf = it & 1;
        __syncthreads();
        if (it + 1 < 8)
            stage_tile(Ah, Al, Wh, Wl, m0, n0, (it + 1) * 64, tid, wv,
                       sAh[buf ^ 1], sAl[buf ^ 1], sWh[buf ^ 1], sWl[buf ^ 1]);
        compute_tile(sAh[buf], sAl[buf], sWh[buf], sWl[buf], wm, wn, ln, qd, 3, accH, accL);
    }

    #pragma unroll
    for (int nt = 0; nt < 2; ++nt) {
        const int gnl = wn * 32 + nt * 16 + ln;
        const int gn = n0 + gnl;
        #pragma unroll
        for (int r = 0; r < 4; ++r) {
            const int mloc = wm * 16 + qd * 4 + r;
            const int m = m0 + mloc;
            float giR = sBi1[0][gnl], giZ = sBi1[1][gnl], giN = sBi1[2][gnl];
            #pragma unroll
            for (int k = 0; k < 8; ++k) {
                const float xv = sX[mloc * 8 + k];
                giR = fmaf(xv, sWi1[0][k][gnl], giR);
                giZ = fmaf(xv, sWi1[1][k][gnl], giZ);
                giN = fmaf(xv, sWi1[2][k][gnl], giN);
            }
            const float gR = giR + sBh1[0][gnl] + accH[0][nt][r] + accL[0][nt][r] * INV_LO;
            const float gZ = giZ + sBh1[1][gnl] + accH[1][nt][r] + accL[1][nt][r] * INV_LO;
            const float gNh = sBh1[2][gnl] + accH[3][nt][r] + accL[3][nt][r] * INV_LO;
            const float R = sigmoidf_(gR), Z = sigmoidf_(gZ);
            const float N = tanhf(fmaf(R, gNh, giN));
            const size_t idx = hidx(m, gn);
            const float hp = (float)Ah[idx] + (float)Al[idx] * INV_LO;
            const float hv = (1.f - Z) * N + Z * hp;
            split_f16(hv, &hnh[idx], &hnl[idx]);
        }
    }
}

__global__ __launch_bounds__(512, 1) void gru2_kernel(
    const _Float16* __restrict__ Aih, const _Float16* __restrict__ Ail,
    const _Float16* __restrict__ Wih, const _Float16* __restrict__ Wil,
    const _Float16* __restrict__ Ahh, const _Float16* __restrict__ Ahl,
    const _Float16* __restrict__ Whh, const _Float16* __restrict__ Whl,
    const float* __restrict__ b_i, const float* __restrict__ b_h,
    _Float16* __restrict__ hnh, _Float16* __restrict__ hnl)
{
    __shared__ _Float16 sAh[2][4096], sAl[2][4096];
    __shared__ _Float16 sWh[2][12288], sWl[2][12288];
    __shared__ float sBi[3][64], sBh[3][64];

    const int tid = threadIdx.x;
    const int wv = tid >> 6, lane = tid & 63;
    const int wm = wv >> 1, wn = wv & 1;
    const int ln = lane & 15, qd = lane >> 4;
    const int n0 = (blockIdx.x & 7) * 64;
    const int m0 = (blockIdx.x >> 3) * 64;

    if (tid < 192) {
        const int g = tid >> 6, n = tid & 63;
        sBi[g][n] = b_i[g * H + n0 + n];
        sBh[g][n] = b_h[g * H + n0 + n];
    }

    float4v accH[4][2], accL[4][2];
    #pragma unroll
    for (int s = 0; s < 4; ++s)
        #pragma unroll
        for (int nt = 0; nt < 2; ++nt) { accH[s][nt] = (float4v)(0.f); accL[s][nt] = (float4v)(0.f); }

    stage_tile(Aih, Ail, Wih, Wil, m0, n0, 0, tid, wv, sAh[0], sAl[0], sWh[0], sWl[0]);
    for (int it = 0; it < 16; ++it) {
        const int buf = it & 1;
        __syncthreads();
        if (it + 1 < 16) {
            const int k0 = ((it + 1) & 7) * 64;
            if (it + 1 < 8)
                stage_tile(Aih, Ail, Wih, Wil, m0, n0, k0, tid, wv,
                           sAh[buf ^ 1], sAl[buf ^ 1], sWh[buf ^ 1], sWl[buf ^ 1]);
            else
                stage_tile(Ahh, Ahl, Whh, Whl, m0, n0, k0, tid, wv,
                           sAh[buf ^ 1], sAl[buf ^ 1], sWh[buf ^ 1], sWl[buf ^ 1]);
        }
        compute_tile(sAh[buf], sAl[buf], sWh[buf], sWl[buf],
                     wm, wn, ln, qd, (it < 8) ? 2 : 3, accH, accL);
    }

    #pragma unroll
    for (int nt = 0; nt < 2; ++nt) {
        const int gnl = wn * 32 + nt * 16 + ln;
        const int gn = n0 + gnl;
        #pragma unroll
        for (int r = 0; r < 4; ++r) {
            const int m = m0 + wm * 16 + qd * 4 + r;
            const float gR = sBi[0][gnl] + sBh[0][gnl] + accH[0][nt][r] + accL[0][nt][r] * INV_LO;
            const float gZ = sBi[1][gnl] + sBh[1][gnl] + accH[1][nt][r] + accL[1][nt][r] * INV_LO;
            const float gNi = sBi[2][gnl] + accH[2][nt][r] + accL[2][nt][r] * INV_LO;
            const float gNh = sBh[2][gnl] + accH[3][nt][r] + accL[3][nt][r] * INV_LO;
            const float R = sigmoidf_(gR), Z = sigmoidf_(gZ);
            const float N = tanhf(fmaf(R, gNh, gNi));
            const size_t idx = hidx(m, gn);
            const float hp = (float)Ahh[idx] + (float)Ahl[idx] * INV_LO;
            const float hv = (1.f - Z) * N + Z * hp;
            split_f16(hv, &hnh[idx], &hnl[idx]);
        }
    }
}

__global__ __launch_bounds__(256) void yout_final_kernel(
    const _Float16* __restrict__ h2h, const _Float16* __restrict__ h2l,
    const float* __restrict__ Wout, const float* __restrict__ bout,
    float* __restrict__ out)
{
    const int wv = threadIdx.x >> 6, lane = threadIdx.x & 63;
    const int b = blockIdx.x * 4 + wv;
    const size_t hb = (size_t)b * H + lane * 8;
    half8 hh = *(const half8*)(h2h + hb);
    half8 hl = *(const half8*)(h2l + hb);
    const int tl = lane >> 3, cw = lane & 7;
    const int kbase = tl * 64 + ((cw ^ (b & 7)) << 3);
    float hv[8];
    #pragma unroll
    for (int j = 0; j < 8; ++j) hv[j] = (float)hh[j] + (float)hl[j] * INV_LO;
    float acc[NO];
    #pragma unroll
    for (int o = 0; o < NO; ++o) {
        acc[o] = 0.f;
        const float* w = Wout + (size_t)o * H + kbase;
        #pragma unroll
        for (int j = 0; j < 8; ++j) acc[o] = fmaf(hv[j], w[j], acc[o]);
    }
    #pragma unroll
    for (int off = 32; off > 0; off >>= 1)
        #pragma unroll
        for (int o = 0; o < NO; ++o) acc[o] += __shfl_down(acc[o], off, 64);
    if (lane == 0) {
        #pragma unroll
        for (int o = 0; o < NO; ++o)
            out[(size_t)b * (T * NO) + (size_t)(T - 1) * NO + o] = acc[o] + bout[o];
    }
}

extern "C" void kernel_launch(void* const* d_in, const int* in_sizes, int n_in,
                              void* d_out, int out_size, void* d_ws, size_t ws_size,
                              hipStream_t stream) {
    (void)in_sizes; (void)n_in; (void)out_size; (void)ws_size;
    const float* cmds  = (const float*)d_in[1];
    const float* y0    = (const float*)d_in[2];
    const float* h01   = (const float*)d_in[3];
    const float* h02   = (const float*)d_in[4];
    const float* W_ih1 = (const float*)d_in[5];
    const float* W_hh1 = (const float*)d_in[6];
    const float* b_ih1 = (const float*)d_in[7];
    const float* b_hh1 = (const float*)d_in[8];
    const float* W_ih2 = (const float*)d_in[9];
    const float* W_hh2 = (const float*)d_in[10];
    const float* b_ih2 = (const float*)d_in[11];
    const float* b_hh2 = (const float*)d_in[12];
    const float* W_out = (const float*)d_in[13];
    const float* b_out = (const float*)d_in[14];
    float* out = (float*)d_out;

    // ---- workspace (~25.6 MB) ----
    char* ws = (char*)d_ws;
    size_t o = 0;
    const size_t WSZ = (size_t)G3H * H * sizeof(_Float16);
    _Float16* wh1h = (_Float16*)(ws + o); o += WSZ;
    _Float16* wh1l = (_Float16*)(ws + o); o += WSZ;
    _Float16* wi2h = (_Float16*)(ws + o); o += WSZ;
    _Float16* wi2l = (_Float16*)(ws + o); o += WSZ;
    _Float16* wh2h = (_Float16*)(ws + o); o += WSZ;
    _Float16* wh2l = (_Float16*)(ws + o); o += WSZ;
    _Float16* h1h = (_Float16*)(ws + o); o += BHE * 2 * 2;   // 2 slots
    _Float16* h1l = (_Float16*)(ws + o); o += BHE * 2 * 2;
    _Float16* h2h = (_Float16*)(ws + o); o += BHE * 2 * 2;
    _Float16* h2l = (_Float16*)(ws + o); o += BHE * 2 * 2;
    float* ybuf = (float*)(ws + o); o += 2 * YS * sizeof(float);

    conv3_kernel<<<(G3H * H + 255) / 256, 256, 0, stream>>>(
        W_hh1, W_ih2, W_hh2, wh1h, wh1l, wi2h, wi2l, wh2h, wh2l);
    prep_kernel<<<(B * H + 255) / 256, 256, 0, stream>>>(
        h01, h02, h1h, h1l, h2h, h2l);

    RP p;
    p.cmds = cmds; p.y0 = y0;
    p.W_ih1 = W_ih1; p.b_ih1 = b_ih1; p.b_hh1 = b_hh1;
    p.b_ih2 = b_ih2; p.b_hh2 = b_hh2;
    p.Wout = W_out; p.bout = b_out;
    p.wh1h = wh1h; p.wh1l = wh1l; p.wi2h = wi2h; p.wi2l = wi2l;
    p.wh2h = wh2h; p.wh2l = wh2l;
    p.h1h = h1h; p.h1l = h1l; p.h2h = h2h; p.h2l = h2l;
    p.ybuf = ybuf; p.out = out;

    void* args[] = { (void*)&p };
    hipError_t err = hipLaunchCooperativeKernel(rnn_persistent, dim3(256), dim3(512),
                                                args, 0, stream);
    if (err != hipSuccess) {
        (void)hipGetLastError();  // clear sticky error; run fallback path
        _Float16* h1hA[2] = { h1h, h1h + BHE };
        _Float16* h1lA[2] = { h1l, h1l + BHE };
        _Float16* h2hA[2] = { h2h, h2h + BHE };
        _Float16* h2lA[2] = { h2l, h2l + BHE };
        for (int t = 0; t < T; ++t) {
            const int si = t & 1, so = si ^ 1;
            gru1_kernel<<<256, 512, 0, stream>>>(
                h1hA[si], h1lA[si], wh1h, wh1l,
                h2hA[si], h2lA[si], W_out, b_out,
                y0, cmds + (size_t)t * B * NC,
                W_ih1, b_ih1, b_hh1,
                h1hA[so], h1lA[so],
                out, t);
            gru2_kernel<<<256, 512, 0, stream>>>(
                h1hA[so], h1lA[so], wi2h, wi2l,
                h2hA[si], h2lA[si], wh2h, wh2l,
                b_ih2, b_hh2,
                h2hA[so], h2lA[so]);
        }
        yout_final_kernel<<<B / 4, 256, 0, stream>>>(
            h2hA[0], h2lA[0], W_out, b_out, out);
    }
}

// Round 3
// 17185.577 us; speedup vs baseline: 1.1186x; 1.1186x over previous
//
#include <hip/hip_runtime.h>
#include <math.h>

// Problem constants
#define B 2048
#define T 128
#define H 512
#define NC 3
#define NO 5
#define G3H 1536
#define BHE ((size_t)B * H)
#define YS ((size_t)B * NO)

typedef _Float16 half8 __attribute__((ext_vector_type(8)));
typedef float float4v __attribute__((ext_vector_type(4)));

#define LO_SCALE 1024.0f
#define INV_LO (1.0f / 1024.0f)
#define F16_MIN_NORM 6.103515625e-05f

__device__ __forceinline__ float sigmoidf_(float x) { return 1.0f / (1.0f + __expf(-x)); }

// Split fp32 -> (hi, lo*1024) f16 pair; hi zeroed in subnormal range (flush safety).
__device__ __forceinline__ void split_f16(float a, _Float16* hi, _Float16* lo) {
    _Float16 h = (_Float16)a;
    if (fabsf(a) < F16_MIN_NORM) h = (_Float16)0.0f;
    *hi = h;
    *lo = (_Float16)((a - (float)h) * LO_SCALE);
}

// element (row,k) of a 512-col matrix stored at row*512 + swzk(row,k):
// 16B chunk c=(k>>3)&7 lives in slot c ^ (row&7)  (LDS-conflict-free fragments)
__device__ __forceinline__ int swzk(int row, int k) {
    return (k & ~63) | ((((k >> 3) & 7) ^ (row & 7)) << 3) | (k & 7);
}
__device__ __forceinline__ size_t hidx(int row, int k) {
    return (size_t)row * H + swzk(row, k);
}

// async 16B global->LDS (wave-uniform LDS base; lane lands at base + lane*16B)
__device__ __forceinline__ void stage16(const _Float16* gp, _Float16* lp) {
    __builtin_amdgcn_global_load_lds(
        (const __attribute__((address_space(1))) unsigned int*)gp,
        (__attribute__((address_space(3))) unsigned int*)lp,
        16, 0, 0);
}

// ---- 8-block group barrier: monotonic arrival counter, no reset, no generation race.
// Each group of 8 blocks (same m0) syncs among themselves only.
__device__ __forceinline__ void group_barrier(unsigned* cnt, unsigned target) {
    __syncthreads();
    if (threadIdx.x == 0) {
        __threadfence();   // release: L2 writeback (agent scope) -> group-mates see our stores
        __hip_atomic_fetch_add(cnt, 1u, __ATOMIC_ACQ_REL, __HIP_MEMORY_SCOPE_AGENT);
        while (__hip_atomic_load(cnt, __ATOMIC_ACQUIRE, __HIP_MEMORY_SCOPE_AGENT) < target) {
            __builtin_amdgcn_s_sleep(1);
        }
        __threadfence();   // acquire: invalidate stale cached lines before consuming
    }
    __syncthreads();
}

// ---------------- prep kernels (once per launch) ----------------
__global__ void conv3_kernel(const float* __restrict__ w1, const float* __restrict__ w2,
                             const float* __restrict__ w3,
                             _Float16* o1h, _Float16* o1l, _Float16* o2h, _Float16* o2l,
                             _Float16* o3h, _Float16* o3l) {
    int i = blockIdx.x * 256 + threadIdx.x;
    if (i < G3H * H) {
        const int r = i >> 9, k = i & 511;
        const size_t d = (size_t)r * H + swzk(r, k);
        split_f16(w1[i], &o1h[d], &o1l[d]);
        split_f16(w2[i], &o2h[d], &o2l[d]);
        split_f16(w3[i], &o3h[d], &o3l[d]);
    }
}

__global__ void prep_kernel(const float* __restrict__ h01, const float* __restrict__ h02,
                            _Float16* h1h, _Float16* h1l, _Float16* h2h, _Float16* h2l,
                            unsigned* bar) {
    int i = blockIdx.x * 256 + threadIdx.x;
    if (i < 32 * 64) bar[i] = 0u;   // zero ALL barrier counters (bug fix: was tid<2048 in a 256-thr block)
    if (i < B * H) {
        const int r = i >> 9, k = i & 511;
        const size_t d = (size_t)r * H + swzk(r, k);
        split_f16(h01[i], &h1h[d], &h1l[d]);
        split_f16(h02[i], &h2h[d], &h2l[d]);
    }
}

// ---------------- staging: one 64x64 K-tile (A 16KB + 3-gate W 48KB) ----------------
// 512 threads: A = 512 chunks (1/thread/component), W = 1536 chunks (3/thread/comp)
__device__ __forceinline__ void stage_tile(
    const _Float16* __restrict__ Ahp, const _Float16* __restrict__ Alp,
    const _Float16* __restrict__ Whp, const _Float16* __restrict__ Wlp,
    int m0, int n0, int k0, int tid, int wv,
    _Float16* sAh, _Float16* sAl, _Float16* sWh, _Float16* sWl)
{
    {
        const int row = tid >> 3, kc = tid & 7;
        const size_t off = (size_t)(m0 + row) * H + k0 + kc * 8;
        stage16(Ahp + off, &sAh[(wv * 64) * 8]);
        stage16(Alp + off, &sAl[(wv * 64) * 8]);
    }
    #pragma unroll
    for (int j = 0; j < 3; ++j) {
        const int cid = j * 512 + tid;
        const int gg = cid >> 9, rem = cid & 511;
        const int nr = rem >> 3, kc = rem & 7;
        const size_t off = (size_t)(gg * H + n0 + nr) * H + k0 + kc * 8;
        stage16(Whp + off, &sWh[(j * 512 + wv * 64) * 8]);
        stage16(Wlp + off, &sWl[(j * 512 + wv * 64) * 8]);
    }
}

// ---------------- old 4-set compute tile (fallback kernels) ----------------
__device__ __forceinline__ void compute_tile(
    const _Float16* sAh, const _Float16* sAl,
    const _Float16* sWh, const _Float16* sWl,
    int wm, int wn, int ln, int qd, int sN,
    float4v (&accH)[4][2], float4v (&accL)[4][2])
{
    #pragma unroll
    for (int ks = 0; ks < 2; ++ks) {
        const int c = ks * 4 + qd;
        const int row = wm * 16 + ln;
        const int ai = row * 64 + ((c ^ (row & 7)) << 3);
        half8 afh = *(const half8*)&sAh[ai];
        half8 afl = *(const half8*)&sAl[ai];
        #pragma unroll
        for (int g = 0; g < 3; ++g) {
            const int s = (g < 2) ? g : sN;
            #pragma unroll
            for (int nt = 0; nt < 2; ++nt) {
                const int nr = wn * 32 + nt * 16 + ln;
                const int wi = (g * 64 + nr) * 64 + ((c ^ (nr & 7)) << 3);
                half8 bh = *(const half8*)&sWh[wi];
                half8 bl = *(const half8*)&sWl[wi];
                accH[s][nt] = __builtin_amdgcn_mfma_f32_16x16x32_f16(afh, bh, accH[s][nt], 0, 0, 0);
                accL[s][nt] = __builtin_amdgcn_mfma_f32_16x16x32_f16(afh, bl, accL[s][nt], 0, 0, 0);
                accL[s][nt] = __builtin_amdgcn_mfma_f32_16x16x32_f16(afl, bh, accL[s][nt], 0, 0, 0);
            }
        }
    }
}

// ---------------- 6-set compute tile, (wm,wn)=(2,4) remap ----------------
// wave covers 32 rows x 16 cols x 3 gates. LDS reads/tile/wave: 20 (was 28).
// SB = accumulator set base (0 for gh1/gi2, 3 for gh2) -- compile-time (rule #20).
template <int SB>
__device__ __forceinline__ void compute_tile6(
    const _Float16* sAh_, const _Float16* sAl_,
    const _Float16* sWh_, const _Float16* sWl_,
    int wm, int wn, int ln, int qd,
    float4v (&accH)[6][2], float4v (&accL)[6][2])
{
    #pragma unroll
    for (int ks = 0; ks < 2; ++ks) {
        const int c = ks * 4 + qd;
        half8 afh[2], afl[2];
        #pragma unroll
        for (int ms = 0; ms < 2; ++ms) {
            const int row = wm * 32 + ms * 16 + ln;
            const int ai = row * 64 + ((c ^ (row & 7)) << 3);
            afh[ms] = *(const half8*)&sAh_[ai];
            afl[ms] = *(const half8*)&sAl_[ai];
        }
        #pragma unroll
        for (int g = 0; g < 3; ++g) {
            const int nr = wn * 16 + ln;
            const int wi = (g * 64 + nr) * 64 + ((c ^ (nr & 7)) << 3);
            half8 bh = *(const half8*)&sWh_[wi];
            half8 bl = *(const half8*)&sWl_[wi];
            #pragma unroll
            for (int ms = 0; ms < 2; ++ms) {
                accH[SB + g][ms] = __builtin_amdgcn_mfma_f32_16x16x32_f16(afh[ms], bh, accH[SB + g][ms], 0, 0, 0);
                accL[SB + g][ms] = __builtin_amdgcn_mfma_f32_16x16x32_f16(afh[ms], bl, accL[SB + g][ms], 0, 0, 0);
                accL[SB + g][ms] = __builtin_amdgcn_mfma_f32_16x16x32_f16(afl[ms], bh, accL[SB + g][ms], 0, 0, 0);
            }
        }
    }
}

// ---------------- persistent kernel (all T steps; 8-block group sync) ----------------
struct RP {
    const float* cmds; const float* y0;
    const float* W_ih1; const float* b_ih1; const float* b_hh1;
    const float* b_ih2; const float* b_hh2;
    const float* Wout; const float* bout;
    const _Float16* wh1h; const _Float16* wh1l;
    const _Float16* wi2h; const _Float16* wi2l;
    const _Float16* wh2h; const _Float16* wh2l;
    _Float16* h1h; _Float16* h1l;   // 2 contiguous slots each
    _Float16* h2h; _Float16* h2l;
    float* ybuf;                    // 2 contiguous slots of B*NO
    float* out;
    unsigned* bar;                  // 32 groups x 64 uints (256B padded counters)
};

__global__ __launch_bounds__(512, 1) void rnn_persistent(RP p) {
    __shared__ _Float16 sAh[2][4096], sAl[2][4096];     // 32 KB
    __shared__ _Float16 sWh[2][12288], sWl[2][12288];   // 96 KB
    __shared__ float sX[64 * 8];
    __shared__ float sWi1[3][8][64];
    __shared__ float sBi1[3][64], sBh1[3][64], sBi2[3][64], sBh2[3][64];
    __shared__ float sWo[NO][64];

    const int tid = threadIdx.x;
    const int wv = tid >> 6, lane = tid & 63;
    const int wm = wv >> 2, wn = wv & 3;                 // (2,4) remap
    const int ln = lane & 15, qd = lane >> 4;
    const int n0 = (blockIdx.x & 7) * 64;                // XCD-local W slice
    const int m0 = (blockIdx.x >> 3) * 64;

    unsigned* gcnt = p.bar + (size_t)(blockIdx.x >> 3) * 64;
    unsigned ep = 0;

    // one-time LDS fills (first K-loop __syncthreads publishes them)
    for (int i = tid; i < 3 * 64 * 8; i += 512) {
        const int g = i >> 9, rem = i & 511, n = rem >> 3, k = rem & 7;
        sWi1[g][k][n] = p.W_ih1[(g * H + n0 + n) * 8 + k];
    }
    if (tid < 192) {
        const int g = tid >> 6, n = tid & 63;
        sBi1[g][n] = p.b_ih1[g * H + n0 + n];
        sBh1[g][n] = p.b_hh1[g * H + n0 + n];
        sBi2[g][n] = p.b_ih2[g * H + n0 + n];
        sBh2[g][n] = p.b_hh2[g * H + n0 + n];
    }
    if (tid < NO * 64)
        sWo[tid >> 6][tid & 63] = p.Wout[(size_t)(tid >> 6) * H + n0 + (tid & 63)];

    // stage phase-1 tile 0 for t=0 (h1 slot 0, W_hh1)
    stage_tile(p.h1h, p.h1l, p.wh1h, p.wh1l, m0, n0, 0, tid, wv,
               sAh[0], sAl[0], sWh[0], sWl[0]);

    float4v accH[6][2], accL[6][2];
    const int gnl = wn * 16 + ln;
    const int gn = n0 + gnl;

    for (int t = 0; t < T; ++t) {
        const int si = t & 1;
        const size_t op = (size_t)si * BHE, on = (size_t)(si ^ 1) * BHE;
        const _Float16* h1ph = p.h1h + op; const _Float16* h1pl = p.h1l + op;
        _Float16* h1nh = p.h1h + on;       _Float16* h1nl = p.h1l + on;
        const _Float16* h2ph = p.h2h + op; const _Float16* h2pl = p.h2l + op;
        _Float16* h2nh = p.h2h + on;       _Float16* h2nl = p.h2l + on;
        float* ybufI = p.ybuf + (size_t)si * YS;             // y[t] accumulates here
        const float* ybufC = p.ybuf + (size_t)(si ^ 1) * YS; // y[t-1] consumed here

        // ---- phase-1 prologue: sX = [y_{t-1}, cmd_t]; out[t-1]; bias-init ybuf[si] ----
        if (t == 0) {
            if (tid < 64) {
                #pragma unroll
                for (int o2 = 0; o2 < NO; ++o2)
                    sX[tid * 8 + o2] = p.y0[(size_t)(m0 + tid) * NO + o2];
            }
        } else if (tid < 64) {
            const float* yr = ybufC + (size_t)(m0 + tid) * NO;
            #pragma unroll
            for (int o2 = 0; o2 < NO; ++o2) {
                const float v = yr[o2];
                sX[tid * 8 + o2] = v;
                if (n0 == 0)
                    p.out[(size_t)(m0 + tid) * (T * NO) + (size_t)(t - 1) * NO + o2] = v;
            }
        }
        if (tid < 64) {
            #pragma unroll
            for (int c = 0; c < NC; ++c)
                sX[tid * 8 + NO + c] =
                    p.cmds[(size_t)t * B * NC + (size_t)(m0 + tid) * NC + c];
        }
        if (n0 == 0 && tid >= 128 && tid < 128 + 64 * NO) {
            const int i = tid - 128;
            ybufI[(size_t)(m0 + i / NO) * NO + (i % NO)] = p.bout[i % NO];
        }

        #pragma unroll
        for (int s = 0; s < 6; ++s)
            #pragma unroll
            for (int ms = 0; ms < 2; ++ms) { accH[s][ms] = (float4v)(0.f); accL[s][ms] = (float4v)(0.f); }

        // ---- phase-1 K-loop: tiles 0-7 gh1 (sets 0-2), 8-15 gh2 (sets 3-5) ----
        for (int it = 0; it < 16; ++it) {
            const int buf = it & 1;
            __syncthreads();
            if (it + 1 < 16) {
                const int k0 = ((it + 1) & 7) * 64;
                if (it + 1 < 8)
                    stage_tile(h1ph, h1pl, p.wh1h, p.wh1l, m0, n0, k0, tid, wv,
                               sAh[buf ^ 1], sAl[buf ^ 1], sWh[buf ^ 1], sWl[buf ^ 1]);
                else
                    stage_tile(h2ph, h2pl, p.wh2h, p.wh2l, m0, n0, k0, tid, wv,
                               sAh[buf ^ 1], sAl[buf ^ 1], sWh[buf ^ 1], sWl[buf ^ 1]);
            }
            if (it < 8)
                compute_tile6<0>(sAh[buf], sAl[buf], sWh[buf], sWl[buf], wm, wn, ln, qd, accH, accL);
            else
                compute_tile6<3>(sAh[buf], sAl[buf], sWh[buf], sWl[buf], wm, wn, ln, qd, accH, accL);
        }

        // ---- epilogue 1: h1[t] = GRU(x, h1[t-1]) ----
        #pragma unroll
        for (int ms = 0; ms < 2; ++ms) {
            #pragma unroll
            for (int r = 0; r < 4; ++r) {
                const int mloc = wm * 32 + ms * 16 + qd * 4 + r;
                const int m = m0 + mloc;
                float giR = sBi1[0][gnl], giZ = sBi1[1][gnl], giN = sBi1[2][gnl];
                #pragma unroll
                for (int k = 0; k < 8; ++k) {
                    const float xv = sX[mloc * 8 + k];
                    giR = fmaf(xv, sWi1[0][k][gnl], giR);
                    giZ = fmaf(xv, sWi1[1][k][gnl], giZ);
                    giN = fmaf(xv, sWi1[2][k][gnl], giN);
                }
                const float gR = giR + sBh1[0][gnl] + accH[0][ms][r] + accL[0][ms][r] * INV_LO;
                const float gZ = giZ + sBh1[1][gnl] + accH[1][ms][r] + accL[1][ms][r] * INV_LO;
                const float gNh = sBh1[2][gnl] + accH[2][ms][r] + accL[2][ms][r] * INV_LO;
                const float R = sigmoidf_(gR), Z = sigmoidf_(gZ);
                const float N = tanhf(fmaf(R, gNh, giN));
                const size_t idx = hidx(m, gn);
                const float hp = (float)h1ph[idx] + (float)h1pl[idx] * INV_LO;
                const float hv = (1.f - Z) * N + Z * hp;
                split_f16(hv, &h1nh[idx], &h1nl[idx]);
            }
        }

        group_barrier(gcnt, 8u * (++ep));   // h1[t] complete within m0-group

        // ---- phase 2: gi2 = h1[t] @ W_ih2^T (sets 0-2 reused; gh2 lives in 3-5) ----
        stage_tile(h1nh, h1nl, p.wi2h, p.wi2l, m0, n0, 0, tid, wv,
                   sAh[0], sAl[0], sWh[0], sWl[0]);
        #pragma unroll
        for (int s = 0; s < 3; ++s)
            #pragma unroll
            for (int ms = 0; ms < 2; ++ms) { accH[s][ms] = (float4v)(0.f); accL[s][ms] = (float4v)(0.f); }

        for (int it = 0; it < 8; ++it) {
            const int buf = it & 1;
            __syncthreads();
            if (it + 1 < 8)
                stage_tile(h1nh, h1nl, p.wi2h, p.wi2l, m0, n0, (it + 1) * 64, tid, wv,
                           sAh[buf ^ 1], sAl[buf ^ 1], sWh[buf ^ 1], sWl[buf ^ 1]);
            else if (t + 1 < T)  // prefetch next phase-1 tile 0 (h1[t] stable since sync) -> buf0
                stage_tile(h1nh, h1nl, p.wh1h, p.wh1l, m0, n0, 0, tid, wv,
                           sAh[0], sAl[0], sWh[0], sWl[0]);
            compute_tile6<0>(sAh[buf], sAl[buf], sWh[buf], sWl[buf], wm, wn, ln, qd, accH, accL);
        }

        // ---- epilogue 2: h2[t] + y[t] partials (shfl over 16 n-cols, then atomics) ----
        #pragma unroll
        for (int ms = 0; ms < 2; ++ms) {
            #pragma unroll
            for (int r = 0; r < 4; ++r) {
                const int mloc = wm * 32 + ms * 16 + qd * 4 + r;
                const int m = m0 + mloc;
                const float gR = sBi2[0][gnl] + accH[0][ms][r] + accL[0][ms][r] * INV_LO
                               + sBh2[0][gnl] + accH[3][ms][r] + accL[3][ms][r] * INV_LO;
                const float gZ = sBi2[1][gnl] + accH[1][ms][r] + accL[1][ms][r] * INV_LO
                               + sBh2[1][gnl] + accH[4][ms][r] + accL[4][ms][r] * INV_LO;
                const float gNi = sBi2[2][gnl] + accH[2][ms][r] + accL[2][ms][r] * INV_LO;
                const float gNh = sBh2[2][gnl] + accH[5][ms][r] + accL[5][ms][r] * INV_LO;
                const float R = sigmoidf_(gR), Z = sigmoidf_(gZ);
                const float N = tanhf(fmaf(R, gNh, gNi));
                const size_t idx = hidx(m, gn);
                const float hp = (float)h2ph[idx] + (float)h2pl[idx] * INV_LO;
                const float hv = (1.f - Z) * N + Z * hp;
                split_f16(hv, &h2nh[idx], &h2nl[idx]);

                float p0 = hv * sWo[0][gnl];
                float p1 = hv * sWo[1][gnl];
                float p2 = hv * sWo[2][gnl];
                float p3 = hv * sWo[3][gnl];
                float p4 = hv * sWo[4][gnl];
                #pragma unroll
                for (int off = 1; off < 16; off <<= 1) {
                    p0 += __shfl_xor(p0, off, 64);
                    p1 += __shfl_xor(p1, off, 64);
                    p2 += __shfl_xor(p2, off, 64);
                    p3 += __shfl_xor(p3, off, 64);
                    p4 += __shfl_xor(p4, off, 64);
                }
                if (ln == 0) {
                    float* yp = ybufI + (size_t)m * NO;
                    atomicAdd(yp + 0, p0);
                    atomicAdd(yp + 1, p1);
                    atomicAdd(yp + 2, p2);
                    atomicAdd(yp + 3, p3);
                    atomicAdd(yp + 4, p4);
                }
            }
        }

        group_barrier(gcnt, 8u * (++ep));   // h2[t], y[t] complete within m0-group
    }

    // final y_{T-1}: slot (T-1)&1 = 1
    if (n0 == 0 && tid < 64 * NO) {
        const int r = tid / NO, o2 = tid % NO;
        p.out[(size_t)(m0 + r) * (T * NO) + (size_t)(T - 1) * NO + o2] =
            p.ybuf[YS + (size_t)(m0 + r) * NO + o2];
    }
}

// ================= fallback path: original per-timestep kernels =================
__global__ __launch_bounds__(512, 1) void gru1_kernel(
    const _Float16* __restrict__ Ah, const _Float16* __restrict__ Al,
    const _Float16* __restrict__ Wh, const _Float16* __restrict__ Wl,
    const _Float16* __restrict__ h2ph, const _Float16* __restrict__ h2pl,
    const float* __restrict__ Wout, const float* __restrict__ bout,
    const float* __restrict__ y0, const float* __restrict__ cmd_t,
    const float* __restrict__ W_ih1,
    const float* __restrict__ b_ih1, const float* __restrict__ b_hh1,
    _Float16* __restrict__ hnh, _Float16* __restrict__ hnl,
    float* __restrict__ out, int t)
{
    __shared__ _Float16 sAh[2][4096], sAl[2][4096];
    __shared__ _Float16 sWh[2][12288], sWl[2][12288];
    __shared__ float sX[64 * 8];
    __shared__ float sWi1[3][8][64];
    __shared__ float sBi1[3][64], sBh1[3][64];

    const int tid = threadIdx.x;
    const int wv = tid >> 6, lane = tid & 63;
    const int wm = wv >> 1, wn = wv & 1;
    const int ln = lane & 15, qd = lane >> 4;
    const int n0 = (blockIdx.x & 7) * 64;
    const int m0 = (blockIdx.x >> 3) * 64;

    for (int i = tid; i < 3 * 64 * 8; i += 512) {
        const int g = i >> 9, rem = i & 511, n = rem >> 3, k = rem & 7;
        sWi1[g][k][n] = W_ih1[(g * H + n0 + n) * 8 + k];
    }
    if (tid < 192) {
        const int g = tid >> 6, n = tid & 63;
        sBi1[g][n] = b_ih1[g * H + n0 + n];
        sBh1[g][n] = b_hh1[g * H + n0 + n];
    }

    float4v accH[4][2], accL[4][2];
    #pragma unroll
    for (int s = 0; s < 4; ++s)
        #pragma unroll
        for (int nt = 0; nt < 2; ++nt) { accH[s][nt] = (float4v)(0.f); accL[s][nt] = (float4v)(0.f); }

    stage_tile(Ah, Al, Wh, Wl, m0, n0, 0, tid, wv, sAh[0], sAl[0], sWh[0], sWl[0]);

    const int yr = tid >> 3, yp = tid & 7;
    if (t == 0) {
        if (tid < 64) {
            #pragma unroll
            for (int o2 = 0; o2 < NO; ++o2)
                sX[tid * 8 + o2] = y0[(size_t)(m0 + tid) * NO + o2];
        }
    } else {
        const int row = m0 + yr;
        float a5[NO] = {0.f, 0.f, 0.f, 0.f, 0.f};
        #pragma unroll
        for (int s = 0; s < 8; ++s) {
            const size_t base = (size_t)row * H + yp * 64 + s * 8;
            half8 hh8 = *(const half8*)(h2ph + base);
            half8 hl8 = *(const half8*)(h2pl + base);
            const int kb = yp * 64 + ((s ^ (row & 7)) << 3);
            #pragma unroll
            for (int j4 = 0; j4 < 2; ++j4) {
                float4 wv4[NO];
                #pragma unroll
                for (int o2 = 0; o2 < NO; ++o2)
                    wv4[o2] = *(const float4*)(Wout + (size_t)o2 * H + kb + j4 * 4);
                #pragma unroll
                for (int jj = 0; jj < 4; ++jj) {
                    const int j = j4 * 4 + jj;
                    const float hv = (float)hh8[j] + (float)hl8[j] * INV_LO;
                    a5[0] = fmaf(hv, ((const float*)&wv4[0])[jj], a5[0]);
                    a5[1] = fmaf(hv, ((const float*)&wv4[1])[jj], a5[1]);
                    a5[2] = fmaf(hv, ((const float*)&wv4[2])[jj], a5[2]);
                    a5[3] = fmaf(hv, ((const float*)&wv4[3])[jj], a5[3]);
                    a5[4] = fmaf(hv, ((const float*)&wv4[4])[jj], a5[4]);
                }
            }
        }
        #pragma unroll
        for (int off = 1; off < 8; off <<= 1)
            #pragma unroll
            for (int o2 = 0; o2 < NO; ++o2) a5[o2] += __shfl_xor(a5[o2], off, 64);
        if (yp == 0) {
            #pragma unroll
            for (int o2 = 0; o2 < NO; ++o2) {
                const float y = a5[o2] + bout[o2];
                sX[yr * 8 + o2] = y;
                if (n0 == 0)
                    out[(size_t)(m0 + yr) * (T * NO) + (size_t)(t - 1) * NO + o2] = y;
            }
        }
    }
    if (tid < 64) {
        #pragma unroll
        for (int c = 0; c < NC; ++c)
            sX[tid * 8 + NO + c] = cmd_t[(size_t)(m0 + tid) * NC + c];
    }

    for (int it = 0; it < 8; ++it) {
        const int buf = it & 1;
        __syncthreads();
        if (it + 1 < 8)
            stage_tile(Ah, Al, Wh, Wl, m0, n0, (it + 1) * 64, tid, wv,
                       sAh[buf ^ 1], sAl[buf ^ 1], sWh[buf ^ 1], sWl[buf ^ 1]);
        compute_tile(sAh[buf], sAl[buf], sWh[buf], sWl[buf], wm, wn, ln, qd, 3, accH, accL);
    }

    #pragma unroll
    for (int nt = 0; nt < 2; ++nt) {
        const int gnl = wn * 32 + nt * 16 + ln;
        const int gn = n0 + gnl;
        #pragma unroll
        for (int r = 0; r < 4; ++r) {
            const int mloc = wm * 16 + qd * 4 + r;
            const int m = m0 + mloc;
            float giR = sBi1[0][gnl], giZ = sBi1[1][gnl], giN = sBi1[2][gnl];
            #pragma unroll
            for (int k = 0; k < 8; ++k) {
                const float xv = sX[mloc * 8 + k];
                giR = fmaf(xv, sWi1[0][k][gnl], giR);
                giZ = fmaf(xv, sWi1[1][k][gnl], giZ);
                giN = fmaf(xv, sWi1[2][k][gnl], giN);
            }
            const float gR = giR + sBh1[0][gnl] + accH[0][nt][r] + accL[0][nt][r] * INV_LO;
            const float gZ = giZ + sBh1[1][gnl] + accH[1][nt][r] + accL[1][nt][r] * INV_LO;
            const float gNh = sBh1[2][gnl] + accH[3][nt][r] + accL[3][nt][r] * INV_LO;
            const float R = sigmoidf_(gR), Z = sigmoidf_(gZ);
            const float N = tanhf(fmaf(R, gNh, giN));
            const size_t idx = hidx(m, gn);
            const float hp = (float)Ah[idx] + (float)Al[idx] * INV_LO;
            const float hv = (1.f - Z) * N + Z * hp;
            split_f16(hv, &hnh[idx], &hnl[idx]);
        }
    }
}

__global__ __launch_bounds__(512, 1) void gru2_kernel(
    const _Float16* __restrict__ Aih, const _Float16* __restrict__ Ail,
    const _Float16* __restrict__ Wih, const _Float16* __restrict__ Wil,
    const _Float16* __restrict__ Ahh, const _Float16* __restrict__ Ahl,
    const _Float16* __restrict__ Whh, const _Float16* __restrict__ Whl,
    const float* __restrict__ b_i, const float* __restrict__ b_h,
    _Float16* __restrict__ hnh, _Float16* __restrict__ hnl)
{
    __shared__ _Float16 sAh[2][4096], sAl[2][4096];
    __shared__ _Float16 sWh[2][12288], sWl[2][12288];
    __shared__ float sBi[3][64], sBh[3][64];

    const int tid = threadIdx.x;
    const int wv = tid >> 6, lane = tid & 63;
    const int wm = wv >> 1, wn = wv & 1;
    const int ln = lane & 15, qd = lane >> 4;
    const int n0 = (blockIdx.x & 7) * 64;
    const int m0 = (blockIdx.x >> 3) * 64;

    if (tid < 192) {
        const int g = tid >> 6, n = tid & 63;
        sBi[g][n] = b_i[g * H + n0 + n];
        sBh[g][n] = b_h[g * H + n0 + n];
    }

    float4v accH[4][2], accL[4][2];
    #pragma unroll
    for (int s = 0; s < 4; ++s)
        #pragma unroll
        for (int nt = 0; nt < 2; ++nt) { accH[s][nt] = (float4v)(0.f); accL[s][nt] = (float4v)(0.f); }

    stage_tile(Aih, Ail, Wih, Wil, m0, n0, 0, tid, wv, sAh[0], sAl[0], sWh[0], sWl[0]);
    for (int it = 0; it < 16; ++it) {
        const int buf = it & 1;
        __syncthreads();
        if (it + 1 < 16) {
            const int k0 = ((it + 1) & 7) * 64;
            if (it + 1 < 8)
                stage_tile(Aih, Ail, Wih, Wil, m0, n0, k0, tid, wv,
                           sAh[buf ^ 1], sAl[buf ^ 1], sWh[buf ^ 1], sWl[buf ^ 1]);
            else
                stage_tile(Ahh, Ahl, Whh, Whl, m0, n0, k0, tid, wv,
                           sAh[buf ^ 1], sAl[buf ^ 1], sWh[buf ^ 1], sWl[buf ^ 1]);
        }
        compute_tile(sAh[buf], sAl[buf], sWh[buf], sWl[buf],
                     wm, wn, ln, qd, (it < 8) ? 2 : 3, accH, accL);
    }

    #pragma unroll
    for (int nt = 0; nt < 2; ++nt) {
        const int gnl = wn * 32 + nt * 16 + ln;
        const int gn = n0 + gnl;
        #pragma unroll
        for (int r = 0; r < 4; ++r) {
            const int m = m0 + wm * 16 + qd * 4 + r;
            const float gR = sBi[0][gnl] + sBh[0][gnl] + accH[0][nt][r] + accL[0][nt][r] * INV_LO;
            const float gZ = sBi[1][gnl] + sBh[1][gnl] + accH[1][nt][r] + accL[1][nt][r] * INV_LO;
            const float gNi = sBi[2][gnl] + accH[2][nt][r] + accL[2][nt][r] * INV_LO;
            const float gNh = sBh[2][gnl] + accH[3][nt][r] + accL[3][nt][r] * INV_LO;
            const float R = sigmoidf_(gR), Z = sigmoidf_(gZ);
            const float N = tanhf(fmaf(R, gNh, gNi));
            const size_t idx = hidx(m, gn);
            const float hp = (float)Ahh[idx] + (float)Ahl[idx] * INV_LO;
            const float hv = (1.f - Z) * N + Z * hp;
            split_f16(hv, &hnh[idx], &hnl[idx]);
        }
    }
}

__global__ __launch_bounds__(256) void yout_final_kernel(
    const _Float16* __restrict__ h2h, const _Float16* __restrict__ h2l,
    const float* __restrict__ Wout, const float* __restrict__ bout,
    float* __restrict__ out)
{
    const int wv = threadIdx.x >> 6, lane = threadIdx.x & 63;
    const int b = blockIdx.x * 4 + wv;
    const size_t hb = (size_t)b * H + lane * 8;
    half8 hh = *(const half8*)(h2h + hb);
    half8 hl = *(const half8*)(h2l + hb);
    const int tl = lane >> 3, cw = lane & 7;
    const int kbase = tl * 64 + ((cw ^ (b & 7)) << 3);
    float hv[8];
    #pragma unroll
    for (int j = 0; j < 8; ++j) hv[j] = (float)hh[j] + (float)hl[j] * INV_LO;
    float acc[NO];
    #pragma unroll
    for (int o = 0; o < NO; ++o) {
        acc[o] = 0.f;
        const float* w = Wout + (size_t)o * H + kbase;
        #pragma unroll
        for (int j = 0; j < 8; ++j) acc[o] = fmaf(hv[j], w[j], acc[o]);
    }
    #pragma unroll
    for (int off = 32; off > 0; off >>= 1)
        #pragma unroll
        for (int o = 0; o < NO; ++o) acc[o] += __shfl_down(acc[o], off, 64);
    if (lane == 0) {
        #pragma unroll
        for (int o = 0; o < NO; ++o)
            out[(size_t)b * (T * NO) + (size_t)(T - 1) * NO + o] = acc[o] + bout[o];
    }
}

extern "C" void kernel_launch(void* const* d_in, const int* in_sizes, int n_in,
                              void* d_out, int out_size, void* d_ws, size_t ws_size,
                              hipStream_t stream) {
    (void)in_sizes; (void)n_in; (void)out_size; (void)ws_size;
    const float* cmds  = (const float*)d_in[1];
    const float* y0    = (const float*)d_in[2];
    const float* h01   = (const float*)d_in[3];
    const float* h02   = (const float*)d_in[4];
    const float* W_ih1 = (const float*)d_in[5];
    const float* W_hh1 = (const float*)d_in[6];
    const float* b_ih1 = (const float*)d_in[7];
    const float* b_hh1 = (const float*)d_in[8];
    const float* W_ih2 = (const float*)d_in[9];
    const float* W_hh2 = (const float*)d_in[10];
    const float* b_ih2 = (const float*)d_in[11];
    const float* b_hh2 = (const float*)d_in[12];
    const float* W_out = (const float*)d_in[13];
    const float* b_out = (const float*)d_in[14];
    float* out = (float*)d_out;

    // ---- workspace (~25.6 MB) ----
    char* ws = (char*)d_ws;
    size_t o = 0;
    const size_t WSZ = (size_t)G3H * H * sizeof(_Float16);
    _Float16* wh1h = (_Float16*)(ws + o); o += WSZ;
    _Float16* wh1l = (_Float16*)(ws + o); o += WSZ;
    _Float16* wi2h = (_Float16*)(ws + o); o += WSZ;
    _Float16* wi2l = (_Float16*)(ws + o); o += WSZ;
    _Float16* wh2h = (_Float16*)(ws + o); o += WSZ;
    _Float16* wh2l = (_Float16*)(ws + o); o += WSZ;
    _Float16* h1h = (_Float16*)(ws + o); o += BHE * 2 * 2;   // 2 slots
    _Float16* h1l = (_Float16*)(ws + o); o += BHE * 2 * 2;
    _Float16* h2h = (_Float16*)(ws + o); o += BHE * 2 * 2;
    _Float16* h2l = (_Float16*)(ws + o); o += BHE * 2 * 2;
    float* ybuf = (float*)(ws + o); o += 2 * YS * sizeof(float);
    unsigned* bar = (unsigned*)(ws + o); o += 32 * 64 * sizeof(unsigned);

    conv3_kernel<<<(G3H * H + 255) / 256, 256, 0, stream>>>(
        W_hh1, W_ih2, W_hh2, wh1h, wh1l, wi2h, wi2l, wh2h, wh2l);
    prep_kernel<<<(B * H + 255) / 256, 256, 0, stream>>>(
        h01, h02, h1h, h1l, h2h, h2l, bar);

    RP p;
    p.cmds = cmds; p.y0 = y0;
    p.W_ih1 = W_ih1; p.b_ih1 = b_ih1; p.b_hh1 = b_hh1;
    p.b_ih2 = b_ih2; p.b_hh2 = b_hh2;
    p.Wout = W_out; p.bout = b_out;
    p.wh1h = wh1h; p.wh1l = wh1l; p.wi2h = wi2h; p.wi2l = wi2l;
    p.wh2h = wh2h; p.wh2l = wh2l;
    p.h1h = h1h; p.h1l = h1l; p.h2h = h2h; p.h2l = h2l;
    p.ybuf = ybuf; p.out = out;
    p.bar = bar;

    void* args[] = { (void*)&p };
    hipError_t err = hipLaunchCooperativeKernel(rnn_persistent, dim3(256), dim3(512),
                                                args, 0, stream);
    if (err != hipSuccess) {
        (void)hipGetLastError();  // clear sticky error; run fallback path
        _Float16* h1hA[2] = { h1h, h1h + BHE };
        _Float16* h1lA[2] = { h1l, h1l + BHE };
        _Float16* h2hA[2] = { h2h, h2h + BHE };
        _Float16* h2lA[2] = { h2l, h2l + BHE };
        for (int t = 0; t < T; ++t) {
            const int si = t & 1, so = si ^ 1;
            gru1_kernel<<<256, 512, 0, stream>>>(
                h1hA[si], h1lA[si], wh1h, wh1l,
                h2hA[si], h2lA[si], W_out, b_out,
                y0, cmds + (size_t)t * B * NC,
                W_ih1, b_ih1, b_hh1,
                h1hA[so], h1lA[so],
                out, t);
            gru2_kernel<<<256, 512, 0, stream>>>(
                h1hA[so], h1lA[so], wi2h, wi2l,
                h2hA[si], h2lA[si], wh2h, wh2l,
                b_ih2, b_hh2,
                h2hA[so], h2lA[so]);
        }
        yout_final_kernel<<<B / 4, 256, 0, stream>>>(
            h2hA[0], h2lA[0], W_out, b_out, out);
    }
}

// Round 4
// 10945.941 us; speedup vs baseline: 1.7563x; 1.5700x over previous
//
#include <hip/hip_runtime.h>
#include <math.h>

// Problem constants
#define B 2048
#define T 128
#define H 512
#define NC 3
#define NO 5
#define G3H 1536
#define BHE ((size_t)B * H)
#define YS ((size_t)B * NO)

typedef _Float16 half8 __attribute__((ext_vector_type(8)));
typedef float float4v __attribute__((ext_vector_type(4)));

#define LO_SCALE 1024.0f
#define INV_LO (1.0f / 1024.0f)
#define F16_MIN_NORM 6.103515625e-05f

__device__ __forceinline__ float sigmoidf_(float x) { return 1.0f / (1.0f + __expf(-x)); }

// Split fp32 -> (hi, lo*1024) f16 pair; hi zeroed in subnormal range (flush safety).
__device__ __forceinline__ void split_f16(float a, _Float16* hi, _Float16* lo) {
    _Float16 h = (_Float16)a;
    if (fabsf(a) < F16_MIN_NORM) h = (_Float16)0.0f;
    *hi = h;
    *lo = (_Float16)((a - (float)h) * LO_SCALE);
}

// element (row,k) of a 512-col matrix stored at row*512 + swzk(row,k):
// 16B chunk c=(k>>3)&7 lives in slot c ^ (row&7)  (LDS-conflict-free fragments)
__device__ __forceinline__ int swzk(int row, int k) {
    return (k & ~63) | ((((k >> 3) & 7) ^ (row & 7)) << 3) | (k & 7);
}
__device__ __forceinline__ size_t hidx(int row, int k) {
    return (size_t)row * H + swzk(row, k);
}

// async 16B global->LDS (wave-uniform LDS base; lane lands at base + lane*16B)
__device__ __forceinline__ void stage16(const _Float16* gp, _Float16* lp) {
    __builtin_amdgcn_global_load_lds(
        (const __attribute__((address_space(1))) unsigned int*)gp,
        (__attribute__((address_space(3))) unsigned int*)lp,
        16, 0, 0);
}

// ---------------- prep kernels (once per launch) ----------------
__global__ void conv3_kernel(const float* __restrict__ w1, const float* __restrict__ w2,
                             const float* __restrict__ w3,
                             _Float16* o1h, _Float16* o1l, _Float16* o2h, _Float16* o2l,
                             _Float16* o3h, _Float16* o3l) {
    int i = blockIdx.x * 256 + threadIdx.x;
    if (i < G3H * H) {
        const int r = i >> 9, k = i & 511;
        const size_t d = (size_t)r * H + swzk(r, k);
        split_f16(w1[i], &o1h[d], &o1l[d]);
        split_f16(w2[i], &o2h[d], &o2l[d]);
        split_f16(w3[i], &o3h[d], &o3l[d]);
    }
}

__global__ void prep_kernel(const float* __restrict__ h01, const float* __restrict__ h02,
                            _Float16* h1h, _Float16* h1l, _Float16* h2h, _Float16* h2l) {
    int i = blockIdx.x * 256 + threadIdx.x;
    if (i < B * H) {
        const int r = i >> 9, k = i & 511;
        const size_t d = (size_t)r * H + swzk(r, k);
        split_f16(h01[i], &h1h[d], &h1l[d]);
        split_f16(h02[i], &h2h[d], &h2l[d]);
    }
}

// ---------------- staging: one 64x64 K-tile (A 16KB + 3-gate W 48KB) ----------------
// 512 threads: A = 512 chunks (1/thread/component), W = 1536 chunks (3/thread/comp)
__device__ __forceinline__ void stage_tile(
    const _Float16* __restrict__ Ahp, const _Float16* __restrict__ Alp,
    const _Float16* __restrict__ Whp, const _Float16* __restrict__ Wlp,
    int m0, int n0, int k0, int tid, int wv,
    _Float16* sAh, _Float16* sAl, _Float16* sWh, _Float16* sWl)
{
    {
        const int row = tid >> 3, kc = tid & 7;
        const size_t off = (size_t)(m0 + row) * H + k0 + kc * 8;
        stage16(Ahp + off, &sAh[(wv * 64) * 8]);
        stage16(Alp + off, &sAl[(wv * 64) * 8]);
    }
    #pragma unroll
    for (int j = 0; j < 3; ++j) {
        const int cid = j * 512 + tid;
        const int gg = cid >> 9, rem = cid & 511;
        const int nr = rem >> 3, kc = rem & 7;
        const size_t off = (size_t)(gg * H + n0 + nr) * H + k0 + kc * 8;
        stage16(Whp + off, &sWh[(j * 512 + wv * 64) * 8]);
        stage16(Wlp + off, &sWl[(j * 512 + wv * 64) * 8]);
    }
}

// ---------------- compute tile, (wm,wn)=(2,4) remap [validated r3] ----------------
// wave covers 32 rows x 16 cols x 3 gates. 20 LDS b128 reads/tile/wave (was 28).
// SB = accumulator set base; NS = total sets (3 for gru1, 6 for gru2).
template <int SB, int NS>
__device__ __forceinline__ void compute_tile24(
    const _Float16* sAh_, const _Float16* sAl_,
    const _Float16* sWh_, const _Float16* sWl_,
    int wm, int wn, int ln, int qd,
    float4v (&accH)[NS][2], float4v (&accL)[NS][2])
{
    #pragma unroll
    for (int ks = 0; ks < 2; ++ks) {
        const int c = ks * 4 + qd;
        half8 afh[2], afl[2];
        #pragma unroll
        for (int ms = 0; ms < 2; ++ms) {
            const int row = wm * 32 + ms * 16 + ln;
            const int ai = row * 64 + ((c ^ (row & 7)) << 3);
            afh[ms] = *(const half8*)&sAh_[ai];
            afl[ms] = *(const half8*)&sAl_[ai];
        }
        #pragma unroll
        for (int g = 0; g < 3; ++g) {
            const int nr = wn * 16 + ln;
            const int wi = (g * 64 + nr) * 64 + ((c ^ (nr & 7)) << 3);
            half8 bh = *(const half8*)&sWh_[wi];
            half8 bl = *(const half8*)&sWl_[wi];
            #pragma unroll
            for (int ms = 0; ms < 2; ++ms) {
                accH[SB + g][ms] = __builtin_amdgcn_mfma_f32_16x16x32_f16(afh[ms], bh, accH[SB + g][ms], 0, 0, 0);
                accL[SB + g][ms] = __builtin_amdgcn_mfma_f32_16x16x32_f16(afh[ms], bl, accL[SB + g][ms], 0, 0, 0);
                accL[SB + g][ms] = __builtin_amdgcn_mfma_f32_16x16x32_f16(afl[ms], bh, accL[SB + g][ms], 0, 0, 0);
            }
        }
    }
}

// ---------------- layer-1 GRU step (y[t-1] read from ybuf; no projection) ----------------
__global__ __launch_bounds__(512, 1) void gru1_kernel(
    const _Float16* __restrict__ h1ph, const _Float16* __restrict__ h1pl,  // h1[t-1] swz
    const _Float16* __restrict__ Wh, const _Float16* __restrict__ Wl,      // wh1 swz
    const float* __restrict__ ybufC,   // y[t-1] (finalized by gru2(t-1))
    const float* __restrict__ y0, const float* __restrict__ cmd_t,
    const float* __restrict__ W_ih1,
    const float* __restrict__ b_ih1, const float* __restrict__ b_hh1,
    const float* __restrict__ bout,
    _Float16* __restrict__ h1nh, _Float16* __restrict__ h1nl,              // h1[t] swz
    float* __restrict__ ybufI,         // y[t] accumulator; bias-init here
    float* __restrict__ out, int t)
{
    __shared__ _Float16 sAh[2][4096], sAl[2][4096];     // 32 KB
    __shared__ _Float16 sWh[2][12288], sWl[2][12288];   // 96 KB
    __shared__ float sX[64 * 8];
    __shared__ float sWi1[3][8][64];
    __shared__ float sBi1[3][64], sBh1[3][64];

    const int tid = threadIdx.x;
    const int wv = tid >> 6, lane = tid & 63;
    const int wm = wv >> 2, wn = wv & 3;                 // (2,4) remap
    const int ln = lane & 15, qd = lane >> 4;
    const int n0 = (blockIdx.x & 7) * 64;                // XCD-local W slice
    const int m0 = (blockIdx.x >> 3) * 64;

    // kick tile 0 first; scalar prologue overlaps its flight
    stage_tile(h1ph, h1pl, Wh, Wl, m0, n0, 0, tid, wv, sAh[0], sAl[0], sWh[0], sWl[0]);

    for (int i = tid; i < 3 * 64 * 8; i += 512) {
        const int g = i >> 9, rem = i & 511, n = rem >> 3, k = rem & 7;
        sWi1[g][k][n] = W_ih1[(g * H + n0 + n) * 8 + k];
    }
    if (tid < 192) {
        const int g = tid >> 6, n = tid & 63;
        sBi1[g][n] = b_ih1[g * H + n0 + n];
        sBh1[g][n] = b_hh1[g * H + n0 + n];
    }

    // sX = [y_{t-1}, cmd_t]; emit out[t-1]; bias-init ybufI for gru2's atomics
    if (t == 0) {
        if (tid < 64) {
            #pragma unroll
            for (int o2 = 0; o2 < NO; ++o2)
                sX[tid * 8 + o2] = y0[(size_t)(m0 + tid) * NO + o2];
        }
    } else if (tid < 64) {
        const float* yr = ybufC + (size_t)(m0 + tid) * NO;
        #pragma unroll
        for (int o2 = 0; o2 < NO; ++o2) {
            const float v = yr[o2];
            sX[tid * 8 + o2] = v;
            if (n0 == 0)
                out[(size_t)(m0 + tid) * (T * NO) + (size_t)(t - 1) * NO + o2] = v;
        }
    }
    if (tid < 64) {
        #pragma unroll
        for (int c = 0; c < NC; ++c)
            sX[tid * 8 + NO + c] = cmd_t[(size_t)(m0 + tid) * NC + c];
    }
    if (n0 == 0 && tid >= 128 && tid < 128 + 64 * NO) {
        const int i = tid - 128;
        ybufI[(size_t)(m0 + i / NO) * NO + (i % NO)] = bout[i % NO];
    }

    float4v accH[3][2], accL[3][2];
    #pragma unroll
    for (int s = 0; s < 3; ++s)
        #pragma unroll
        for (int ms = 0; ms < 2; ++ms) { accH[s][ms] = (float4v)(0.f); accL[s][ms] = (float4v)(0.f); }

    // K-loop: gh1 = h1[t-1] @ W_hh1^T (8 tiles, dbuf)
    for (int it = 0; it < 8; ++it) {
        const int buf = it & 1;
        __syncthreads();
        if (it + 1 < 8)
            stage_tile(h1ph, h1pl, Wh, Wl, m0, n0, (it + 1) * 64, tid, wv,
                       sAh[buf ^ 1], sAl[buf ^ 1], sWh[buf ^ 1], sWl[buf ^ 1]);
        compute_tile24<0, 3>(sAh[buf], sAl[buf], sWh[buf], sWl[buf], wm, wn, ln, qd, accH, accL);
    }

    // epilogue: fp32 input path (K=8) + gates + blend -> h1[t]
    const int gnl = wn * 16 + ln;
    const int gn = n0 + gnl;
    #pragma unroll
    for (int ms = 0; ms < 2; ++ms) {
        #pragma unroll
        for (int r = 0; r < 4; ++r) {
            const int mloc = wm * 32 + ms * 16 + qd * 4 + r;
            const int m = m0 + mloc;
            float giR = sBi1[0][gnl], giZ = sBi1[1][gnl], giN = sBi1[2][gnl];
            #pragma unroll
            for (int k = 0; k < 8; ++k) {
                const float xv = sX[mloc * 8 + k];
                giR = fmaf(xv, sWi1[0][k][gnl], giR);
                giZ = fmaf(xv, sWi1[1][k][gnl], giZ);
                giN = fmaf(xv, sWi1[2][k][gnl], giN);
            }
            const float gR = giR + sBh1[0][gnl] + accH[0][ms][r] + accL[0][ms][r] * INV_LO;
            const float gZ = giZ + sBh1[1][gnl] + accH[1][ms][r] + accL[1][ms][r] * INV_LO;
            const float gNh = sBh1[2][gnl] + accH[2][ms][r] + accL[2][ms][r] * INV_LO;
            const float R = sigmoidf_(gR), Z = sigmoidf_(gZ);
            const float N = tanhf(fmaf(R, gNh, giN));
            const size_t idx = hidx(m, gn);
            const float hp = (float)h1ph[idx] + (float)h1pl[idx] * INV_LO;
            const float hv = (1.f - Z) * N + Z * hp;
            split_f16(hv, &h1nh[idx], &h1nl[idx]);
        }
    }
}

// ---------------- layer-2 GRU step (+ fused y[t] partials) ----------------
__global__ __launch_bounds__(512, 1) void gru2_kernel(
    const _Float16* __restrict__ h1nh, const _Float16* __restrict__ h1nl,  // h1[t] swz
    const _Float16* __restrict__ Wih, const _Float16* __restrict__ Wil,    // wi2 swz
    const _Float16* __restrict__ h2ph, const _Float16* __restrict__ h2pl,  // h2[t-1] swz
    const _Float16* __restrict__ Whh, const _Float16* __restrict__ Whl,    // wh2 swz
    const float* __restrict__ b_i, const float* __restrict__ b_h,
    const float* __restrict__ Wout,
    _Float16* __restrict__ h2nh, _Float16* __restrict__ h2nl,              // h2[t] swz
    float* __restrict__ ybufI)         // y[t] accumulator (bias-init'd by gru1)
{
    __shared__ _Float16 sAh[2][4096], sAl[2][4096];
    __shared__ _Float16 sWh[2][12288], sWl[2][12288];
    __shared__ float sBi[3][64], sBh[3][64];
    __shared__ float sWo[NO][64];

    const int tid = threadIdx.x;
    const int wv = tid >> 6, lane = tid & 63;
    const int wm = wv >> 2, wn = wv & 3;                 // (2,4) remap
    const int ln = lane & 15, qd = lane >> 4;
    const int n0 = (blockIdx.x & 7) * 64;
    const int m0 = (blockIdx.x >> 3) * 64;

    stage_tile(h1nh, h1nl, Wih, Wil, m0, n0, 0, tid, wv, sAh[0], sAl[0], sWh[0], sWl[0]);

    if (tid < 192) {
        const int g = tid >> 6, n = tid & 63;
        sBi[g][n] = b_i[g * H + n0 + n];
        sBh[g][n] = b_h[g * H + n0 + n];
    }
    if (tid < NO * 64)
        sWo[tid >> 6][tid & 63] = Wout[(size_t)(tid >> 6) * H + n0 + (tid & 63)];

    float4v accH[6][2], accL[6][2];
    #pragma unroll
    for (int s = 0; s < 6; ++s)
        #pragma unroll
        for (int ms = 0; ms < 2; ++ms) { accH[s][ms] = (float4v)(0.f); accL[s][ms] = (float4v)(0.f); }

    // K-loop: tiles 0-7 gi2 (sets 0-2, A=h1[t]), tiles 8-15 gh2 (sets 3-5, A=h2[t-1])
    for (int it = 0; it < 16; ++it) {
        const int buf = it & 1;
        __syncthreads();
        if (it + 1 < 16) {
            const int k0 = ((it + 1) & 7) * 64;
            if (it + 1 < 8)
                stage_tile(h1nh, h1nl, Wih, Wil, m0, n0, k0, tid, wv,
                           sAh[buf ^ 1], sAl[buf ^ 1], sWh[buf ^ 1], sWl[buf ^ 1]);
            else
                stage_tile(h2ph, h2pl, Whh, Whl, m0, n0, k0, tid, wv,
                           sAh[buf ^ 1], sAl[buf ^ 1], sWh[buf ^ 1], sWl[buf ^ 1]);
        }
        if (it < 8)
            compute_tile24<0, 6>(sAh[buf], sAl[buf], sWh[buf], sWl[buf], wm, wn, ln, qd, accH, accL);
        else
            compute_tile24<3, 6>(sAh[buf], sAl[buf], sWh[buf], sWl[buf], wm, wn, ln, qd, accH, accL);
    }

    // epilogue: h2[t] + y[t] partials (shfl over 16 n-cols, then 5 atomics/row-group)
    const int gnl = wn * 16 + ln;
    const int gn = n0 + gnl;
    #pragma unroll
    for (int ms = 0; ms < 2; ++ms) {
        #pragma unroll
        for (int r = 0; r < 4; ++r) {
            const int mloc = wm * 32 + ms * 16 + qd * 4 + r;
            const int m = m0 + mloc;
            const float gR = sBi[0][gnl] + accH[0][ms][r] + accL[0][ms][r] * INV_LO
                           + sBh[0][gnl] + accH[3][ms][r] + accL[3][ms][r] * INV_LO;
            const float gZ = sBi[1][gnl] + accH[1][ms][r] + accL[1][ms][r] * INV_LO
                           + sBh[1][gnl] + accH[4][ms][r] + accL[4][ms][r] * INV_LO;
            const float gNi = sBi[2][gnl] + accH[2][ms][r] + accL[2][ms][r] * INV_LO;
            const float gNh = sBh[2][gnl] + accH[5][ms][r] + accL[5][ms][r] * INV_LO;
            const float R = sigmoidf_(gR), Z = sigmoidf_(gZ);
            const float N = tanhf(fmaf(R, gNh, gNi));
            const size_t idx = hidx(m, gn);
            const float hp = (float)h2ph[idx] + (float)h2pl[idx] * INV_LO;
            const float hv = (1.f - Z) * N + Z * hp;
            split_f16(hv, &h2nh[idx], &h2nl[idx]);

            float p0 = hv * sWo[0][gnl];
            float p1 = hv * sWo[1][gnl];
            float p2 = hv * sWo[2][gnl];
            float p3 = hv * sWo[3][gnl];
            float p4 = hv * sWo[4][gnl];
            #pragma unroll
            for (int off = 1; off < 16; off <<= 1) {
                p0 += __shfl_xor(p0, off, 64);
                p1 += __shfl_xor(p1, off, 64);
                p2 += __shfl_xor(p2, off, 64);
                p3 += __shfl_xor(p3, off, 64);
                p4 += __shfl_xor(p4, off, 64);
            }
            if (ln == 0) {
                float* yp = ybufI + (size_t)m * NO;
                atomicAdd(yp + 0, p0);
                atomicAdd(yp + 1, p1);
                atomicAdd(yp + 2, p2);
                atomicAdd(yp + 3, p3);
                atomicAdd(yp + 4, p4);
            }
        }
    }
}

// ---------------- tail: out[:, T-1, :] <- ybuf slot 1 ----------------
__global__ void yfin_kernel(const float* __restrict__ ybuf1, float* __restrict__ out) {
    int i = blockIdx.x * 256 + threadIdx.x;
    if (i < B * NO) {
        const int b = i / NO, o = i % NO;
        out[(size_t)b * (T * NO) + (size_t)(T - 1) * NO + o] = ybuf1[i];
    }
}

extern "C" void kernel_launch(void* const* d_in, const int* in_sizes, int n_in,
                              void* d_out, int out_size, void* d_ws, size_t ws_size,
                              hipStream_t stream) {
    (void)in_sizes; (void)n_in; (void)out_size; (void)ws_size;
    const float* cmds  = (const float*)d_in[1];
    const float* y0    = (const float*)d_in[2];
    const float* h01   = (const float*)d_in[3];
    const float* h02   = (const float*)d_in[4];
    const float* W_ih1 = (const float*)d_in[5];
    const float* W_hh1 = (const float*)d_in[6];
    const float* b_ih1 = (const float*)d_in[7];
    const float* b_hh1 = (const float*)d_in[8];
    const float* W_ih2 = (const float*)d_in[9];
    const float* W_hh2 = (const float*)d_in[10];
    const float* b_ih2 = (const float*)d_in[11];
    const float* b_hh2 = (const float*)d_in[12];
    const float* W_out = (const float*)d_in[13];
    const float* b_out = (const float*)d_in[14];
    float* out = (float*)d_out;

    // ---- workspace (~25.6 MB) ----
    char* ws = (char*)d_ws;
    size_t o = 0;
    const size_t WSZ = (size_t)G3H * H * sizeof(_Float16);
    _Float16* wh1h = (_Float16*)(ws + o); o += WSZ;
    _Float16* wh1l = (_Float16*)(ws + o); o += WSZ;
    _Float16* wi2h = (_Float16*)(ws + o); o += WSZ;
    _Float16* wi2l = (_Float16*)(ws + o); o += WSZ;
    _Float16* wh2h = (_Float16*)(ws + o); o += WSZ;
    _Float16* wh2l = (_Float16*)(ws + o); o += WSZ;
    _Float16* h1h = (_Float16*)(ws + o); o += BHE * 2 * 2;   // 2 slots
    _Float16* h1l = (_Float16*)(ws + o); o += BHE * 2 * 2;
    _Float16* h2h = (_Float16*)(ws + o); o += BHE * 2 * 2;
    _Float16* h2l = (_Float16*)(ws + o); o += BHE * 2 * 2;
    float* ybuf = (float*)(ws + o); o += 2 * YS * sizeof(float);

    conv3_kernel<<<(G3H * H + 255) / 256, 256, 0, stream>>>(
        W_hh1, W_ih2, W_hh2, wh1h, wh1l, wi2h, wi2l, wh2h, wh2l);
    prep_kernel<<<(B * H + 255) / 256, 256, 0, stream>>>(
        h01, h02, h1h, h1l, h2h, h2l);

    _Float16* h1hA[2] = { h1h, h1h + BHE };
    _Float16* h1lA[2] = { h1l, h1l + BHE };
    _Float16* h2hA[2] = { h2h, h2h + BHE };
    _Float16* h2lA[2] = { h2l, h2l + BHE };

    for (int t = 0; t < T; ++t) {
        const int si = t & 1, so = si ^ 1;
        float* ybufI = ybuf + (size_t)si * YS;        // y[t] accumulates here
        const float* ybufC = ybuf + (size_t)so * YS;  // y[t-1] consumed here

        gru1_kernel<<<256, 512, 0, stream>>>(
            h1hA[si], h1lA[si], wh1h, wh1l,
            ybufC, y0, cmds + (size_t)t * B * NC,
            W_ih1, b_ih1, b_hh1, b_out,
            h1hA[so], h1lA[so],
            ybufI, out, t);

        gru2_kernel<<<256, 512, 0, stream>>>(
            h1hA[so], h1lA[so], wi2h, wi2l,
            h2hA[si], h2lA[si], wh2h, wh2l,
            b_ih2, b_hh2, W_out,
            h2hA[so], h2lA[so],
            ybufI);
    }

    // T even -> y[T-1] sits in ybuf slot 1
    yfin_kernel<<<(B * NO + 255) / 256, 256, 0, stream>>>(ybuf + YS, out);
}

// Round 6
// 9069.229 us; speedup vs baseline: 2.1197x; 1.2069x over previous
//
#include <hip/hip_runtime.h>
#include <math.h>

// Problem constants
#define B 2048
#define T 128
#define H 512
#define NC 3
#define NO 5
#define G3H 1536
#define BHE ((size_t)B * H)

typedef _Float16 half8 __attribute__((ext_vector_type(8)));
typedef float float4v __attribute__((ext_vector_type(4)));

#define LO_SCALE 1024.0f
#define INV_LO (1.0f / 1024.0f)
#define F16_MIN_NORM 6.103515625e-05f

__device__ __forceinline__ float sigmoidf_(float x) { return 1.0f / (1.0f + __expf(-x)); }

// Split fp32 -> (hi, lo*1024) f16 pair; hi zeroed in subnormal range (flush safety).
__device__ __forceinline__ void split_f16(float a, _Float16* hi, _Float16* lo) {
    _Float16 h = (_Float16)a;
    if (fabsf(a) < F16_MIN_NORM) h = (_Float16)0.0f;
    *hi = h;
    *lo = (_Float16)((a - (float)h) * LO_SCALE);
}

// element (row,k) of a 512-col matrix stored at row*512 + swzk(row,k):
// 16B chunk c=(k>>3)&7 lives in slot c ^ (row&7)  (LDS-conflict-free fragments)
__device__ __forceinline__ int swzk(int row, int k) {
    return (k & ~63) | ((((k >> 3) & 7) ^ (row & 7)) << 3) | (k & 7);
}
__device__ __forceinline__ size_t hidx(int row, int k) {
    return (size_t)row * H + swzk(row, k);
}

// async 16B global->LDS (wave-uniform LDS base; lane lands at base + lane*16B)
__device__ __forceinline__ void stage16(const _Float16* gp, _Float16* lp) {
    __builtin_amdgcn_global_load_lds(
        (const __attribute__((address_space(1))) unsigned int*)gp,
        (__attribute__((address_space(3))) unsigned int*)lp,
        16, 0, 0);
}

// ---------------- prep kernels (once per launch) ----------------
__global__ void conv3_kernel(const float* __restrict__ w1, const float* __restrict__ w2,
                             const float* __restrict__ w3,
                             _Float16* o1h, _Float16* o1l, _Float16* o2h, _Float16* o2l,
                             _Float16* o3h, _Float16* o3l) {
    int i = blockIdx.x * 256 + threadIdx.x;
    if (i < G3H * H) {
        const int r = i >> 9, k = i & 511;
        const size_t d = (size_t)r * H + swzk(r, k);
        split_f16(w1[i], &o1h[d], &o1l[d]);
        split_f16(w2[i], &o2h[d], &o2l[d]);
        split_f16(w3[i], &o3h[d], &o3l[d]);
    }
}

__global__ void prep_kernel(const float* __restrict__ h01, const float* __restrict__ h02,
                            _Float16* h1h, _Float16* h1l, _Float16* h2h, _Float16* h2l) {
    int i = blockIdx.x * 256 + threadIdx.x;
    if (i < B * H) {
        const int r = i >> 9, k = i & 511;
        const size_t d = (size_t)r * H + swzk(r, k);
        split_f16(h01[i], &h1h[d], &h1l[d]);
        split_f16(h02[i], &h2h[d], &h2l[d]);
    }
}

// ---------------- staging: one 64x64 K-tile (A 16KB + 3-gate W 48KB) ----------------
// 512 threads: A = 512 chunks (1/thread/component), W = 1536 chunks (3/thread/comp)
__device__ __forceinline__ void stage_tile(
    const _Float16* __restrict__ Ahp, const _Float16* __restrict__ Alp,
    const _Float16* __restrict__ Whp, const _Float16* __restrict__ Wlp,
    int m0, int n0, int k0, int tid, int wv,
    _Float16* sAh, _Float16* sAl, _Float16* sWh, _Float16* sWl)
{
    {
        const int row = tid >> 3, kc = tid & 7;
        const size_t off = (size_t)(m0 + row) * H + k0 + kc * 8;
        stage16(Ahp + off, &sAh[(wv * 64) * 8]);
        stage16(Alp + off, &sAl[(wv * 64) * 8]);
    }
    #pragma unroll
    for (int j = 0; j < 3; ++j) {
        const int cid = j * 512 + tid;
        const int gg = cid >> 9, rem = cid & 511;
        const int nr = rem >> 3, kc = rem & 7;
        const size_t off = (size_t)(gg * H + n0 + nr) * H + k0 + kc * 8;
        stage16(Whp + off, &sWh[(j * 512 + wv * 64) * 8]);
        stage16(Wlp + off, &sWl[(j * 512 + wv * 64) * 8]);
    }
}

// ---------------- compute tile, (wm,wn)=(2,4) remap — ONLY change vs round-0 ----------------
// wave covers 32 rows x 16 cols x 3 gates: 20 ds_read_b128/tile/wave (was 28), same 36 MFMA.
// Baseline 4-set acc layout kept: gates R,Z -> sets 0,1 (shared across phases); N -> set SN.
template <int SN>
__device__ __forceinline__ void compute_tile24(
    const _Float16* sAh_, const _Float16* sAl_,
    const _Float16* sWh_, const _Float16* sWl_,
    int wm, int wn, int ln, int qd,
    float4v (&accH)[4][2], float4v (&accL)[4][2])
{
    #pragma unroll
    for (int ks = 0; ks < 2; ++ks) {
        const int c = ks * 4 + qd;
        half8 afh[2], afl[2];
        #pragma unroll
        for (int ms = 0; ms < 2; ++ms) {
            const int row = wm * 32 + ms * 16 + ln;
            const int ai = row * 64 + ((c ^ (row & 7)) << 3);
            afh[ms] = *(const half8*)&sAh_[ai];
            afl[ms] = *(const half8*)&sAl_[ai];
        }
        #pragma unroll
        for (int g = 0; g < 3; ++g) {
            const int s = (g < 2) ? g : SN;
            const int nr = wn * 16 + ln;
            const int wi = (g * 64 + nr) * 64 + ((c ^ (nr & 7)) << 3);
            half8 bh = *(const half8*)&sWh_[wi];
            half8 bl = *(const half8*)&sWl_[wi];
            #pragma unroll
            for (int ms = 0; ms < 2; ++ms) {
                accH[s][ms] = __builtin_amdgcn_mfma_f32_16x16x32_f16(afh[ms], bh, accH[s][ms], 0, 0, 0);
                accL[s][ms] = __builtin_amdgcn_mfma_f32_16x16x32_f16(afh[ms], bl, accL[s][ms], 0, 0, 0);
                accL[s][ms] = __builtin_amdgcn_mfma_f32_16x16x32_f16(afl[ms], bh, accL[s][ms], 0, 0, 0);
            }
        }
    }
}

// ---------------- layer-1 GRU step (+ fused y_{t-1} projection) — baseline structure ----------------
__global__ __launch_bounds__(512, 1) void gru1_kernel(
    const _Float16* __restrict__ Ah, const _Float16* __restrict__ Al,    // h1 prev swz
    const _Float16* __restrict__ Wh, const _Float16* __restrict__ Wl,    // wh1 swz
    const _Float16* __restrict__ h2ph, const _Float16* __restrict__ h2pl,// h2 prev swz
    const float* __restrict__ Wout, const float* __restrict__ bout,
    const float* __restrict__ y0, const float* __restrict__ cmd_t,
    const float* __restrict__ W_ih1,
    const float* __restrict__ b_ih1, const float* __restrict__ b_hh1,
    _Float16* __restrict__ hnh, _Float16* __restrict__ hnl,
    float* __restrict__ out, int t)
{
    __shared__ _Float16 sAh[2][4096], sAl[2][4096];     // 32 KB
    __shared__ _Float16 sWh[2][12288], sWl[2][12288];   // 96 KB
    __shared__ float sX[64 * 8];
    __shared__ float sWi1[3][8][64];
    __shared__ float sBi1[3][64], sBh1[3][64];

    const int tid = threadIdx.x;
    const int wv = tid >> 6, lane = tid & 63;
    const int wm = wv >> 2, wn = wv & 3;                 // (2,4) remap
    const int ln = lane & 15, qd = lane >> 4;
    const int n0 = (blockIdx.x & 7) * 64;
    const int m0 = (blockIdx.x >> 3) * 64;

    // one-time LDS fills (consumed after K-loop syncs)
    for (int i = tid; i < 3 * 64 * 8; i += 512) {
        const int g = i >> 9, rem = i & 511, n = rem >> 3, k = rem & 7;
        sWi1[g][k][n] = W_ih1[(g * H + n0 + n) * 8 + k];
    }
    if (tid < 192) {
        const int g = tid >> 6, n = tid & 63;
        sBi1[g][n] = b_ih1[g * H + n0 + n];
        sBh1[g][n] = b_hh1[g * H + n0 + n];
    }

    float4v accH[4][2], accL[4][2];
    #pragma unroll
    for (int s = 0; s < 4; ++s)
        #pragma unroll
        for (int ms = 0; ms < 2; ++ms) { accH[s][ms] = (float4v)(0.f); accL[s][ms] = (float4v)(0.f); }

    // kick off tile 0 (async), then overlap the y-projection with its flight
    stage_tile(Ah, Al, Wh, Wl, m0, n0, 0, tid, wv, sAh[0], sAl[0], sWh[0], sWl[0]);

    // ---- y_{t-1} = h2_prev . Wout^T + bout (this block's 64 rows) ----
    const int yr = tid >> 3, yp = tid & 7;   // row, K-octant
    if (t == 0) {
        if (tid < 64) {
            #pragma unroll
            for (int o2 = 0; o2 < NO; ++o2)
                sX[tid * 8 + o2] = y0[(size_t)(m0 + tid) * NO + o2];
        }
    } else {
        const int row = m0 + yr;
        float a5[NO] = {0.f, 0.f, 0.f, 0.f, 0.f};
        #pragma unroll
        for (int s = 0; s < 8; ++s) {
            const size_t base = (size_t)row * H + yp * 64 + s * 8;
            half8 hh8 = *(const half8*)(h2ph + base);
            half8 hl8 = *(const half8*)(h2pl + base);
            const int kb = yp * 64 + ((s ^ (row & 7)) << 3);
            #pragma unroll
            for (int j4 = 0; j4 < 2; ++j4) {
                float4 wv4[NO];
                #pragma unroll
                for (int o2 = 0; o2 < NO; ++o2)
                    wv4[o2] = *(const float4*)(Wout + (size_t)o2 * H + kb + j4 * 4);
                #pragma unroll
                for (int jj = 0; jj < 4; ++jj) {
                    const int j = j4 * 4 + jj;
                    const float hv = (float)hh8[j] + (float)hl8[j] * INV_LO;
                    a5[0] = fmaf(hv, ((const float*)&wv4[0])[jj], a5[0]);
                    a5[1] = fmaf(hv, ((const float*)&wv4[1])[jj], a5[1]);
                    a5[2] = fmaf(hv, ((const float*)&wv4[2])[jj], a5[2]);
                    a5[3] = fmaf(hv, ((const float*)&wv4[3])[jj], a5[3]);
                    a5[4] = fmaf(hv, ((const float*)&wv4[4])[jj], a5[4]);
                }
            }
        }
        #pragma unroll
        for (int off = 1; off < 8; off <<= 1)
            #pragma unroll
            for (int o2 = 0; o2 < NO; ++o2) a5[o2] += __shfl_xor(a5[o2], off, 64);
        if (yp == 0) {
            #pragma unroll
            for (int o2 = 0; o2 < NO; ++o2) {
                const float y = a5[o2] + bout[o2];
                sX[yr * 8 + o2] = y;
                if (n0 == 0)
                    out[(size_t)(m0 + yr) * (T * NO) + (size_t)(t - 1) * NO + o2] = y;
            }
        }
    }
    if (tid < 64) {
        #pragma unroll
        for (int c = 0; c < NC; ++c)
            sX[tid * 8 + NO + c] = cmd_t[(size_t)(m0 + tid) * NC + c];
    }

    // ---- K-loop: gh = h1_prev @ W_hh1^T (8 tiles), n-gate -> set 3 ----
    for (int it = 0; it < 8; ++it) {
        const int buf = it & 1;
        __syncthreads();
        if (it + 1 < 8)
            stage_tile(Ah, Al, Wh, Wl, m0, n0, (it + 1) * 64, tid, wv,
                       sAh[buf ^ 1], sAl[buf ^ 1], sWh[buf ^ 1], sWl[buf ^ 1]);
        compute_tile24<3>(sAh[buf], sAl[buf], sWh[buf], sWl[buf], wm, wn, ln, qd, accH, accL);
    }

    // ---- epilogue: fp32 input path (K=8) + gates + blend ----
    const int gnl = wn * 16 + ln;
    const int gn = n0 + gnl;
    #pragma unroll
    for (int ms = 0; ms < 2; ++ms) {
        #pragma unroll
        for (int r = 0; r < 4; ++r) {
            const int mloc = wm * 32 + ms * 16 + qd * 4 + r;
            const int m = m0 + mloc;
            float giR = sBi1[0][gnl], giZ = sBi1[1][gnl], giN = sBi1[2][gnl];
            #pragma unroll
            for (int k = 0; k < 8; ++k) {
                const float xv = sX[mloc * 8 + k];
                giR = fmaf(xv, sWi1[0][k][gnl], giR);
                giZ = fmaf(xv, sWi1[1][k][gnl], giZ);
                giN = fmaf(xv, sWi1[2][k][gnl], giN);
            }
            const float gR = giR + sBh1[0][gnl] + accH[0][ms][r] + accL[0][ms][r] * INV_LO;
            const float gZ = giZ + sBh1[1][gnl] + accH[1][ms][r] + accL[1][ms][r] * INV_LO;
            const float gNh = sBh1[2][gnl] + accH[3][ms][r] + accL[3][ms][r] * INV_LO;
            const float R = sigmoidf_(gR), Z = sigmoidf_(gZ);
            const float N = tanhf(fmaf(R, gNh, giN));
            const size_t idx = hidx(m, gn);
            const float hp = (float)Ah[idx] + (float)Al[idx] * INV_LO;
            const float hv = (1.f - Z) * N + Z * hp;
            split_f16(hv, &hnh[idx], &hnl[idx]);
        }
    }
}

// ---------------- layer-2 GRU step — baseline structure ----------------
__global__ __launch_bounds__(512, 1) void gru2_kernel(
    const _Float16* __restrict__ Aih, const _Float16* __restrict__ Ail,  // h1 cur swz
    const _Float16* __restrict__ Wih, const _Float16* __restrict__ Wil,  // wi2 swz
    const _Float16* __restrict__ Ahh, const _Float16* __restrict__ Ahl,  // h2 prev swz
    const _Float16* __restrict__ Whh, const _Float16* __restrict__ Whl,  // wh2 swz
    const float* __restrict__ b_i, const float* __restrict__ b_h,
    _Float16* __restrict__ hnh, _Float16* __restrict__ hnl)
{
    __shared__ _Float16 sAh[2][4096], sAl[2][4096];
    __shared__ _Float16 sWh[2][12288], sWl[2][12288];
    __shared__ float sBi[3][64], sBh[3][64];

    const int tid = threadIdx.x;
    const int wv = tid >> 6, lane = tid & 63;
    const int wm = wv >> 2, wn = wv & 3;                 // (2,4) remap
    const int ln = lane & 15, qd = lane >> 4;
    const int n0 = (blockIdx.x & 7) * 64;
    const int m0 = (blockIdx.x >> 3) * 64;

    if (tid < 192) {
        const int g = tid >> 6, n = tid & 63;
        sBi[g][n] = b_i[g * H + n0 + n];
        sBh[g][n] = b_h[g * H + n0 + n];
    }

    float4v accH[4][2], accL[4][2];
    #pragma unroll
    for (int s = 0; s < 4; ++s)
        #pragma unroll
        for (int ms = 0; ms < 2; ++ms) { accH[s][ms] = (float4v)(0.f); accL[s][ms] = (float4v)(0.f); }

    stage_tile(Aih, Ail, Wih, Wil, m0, n0, 0, tid, wv, sAh[0], sAl[0], sWh[0], sWl[0]);
    for (int it = 0; it < 16; ++it) {
        const int buf = it & 1;
        __syncthreads();
        if (it + 1 < 16) {
            const int k0 = ((it + 1) & 7) * 64;
            if (it + 1 < 8)
                stage_tile(Aih, Ail, Wih, Wil, m0, n0, k0, tid, wv,
                           sAh[buf ^ 1], sAl[buf ^ 1], sWh[buf ^ 1], sWl[buf ^ 1]);
            else
                stage_tile(Ahh, Ahl, Whh, Whl, m0, n0, k0, tid, wv,
                           sAh[buf ^ 1], sAl[buf ^ 1], sWh[buf ^ 1], sWl[buf ^ 1]);
        }
        if (it < 8)
            compute_tile24<2>(sAh[buf], sAl[buf], sWh[buf], sWl[buf], wm, wn, ln, qd, accH, accL);
        else
            compute_tile24<3>(sAh[buf], sAl[buf], sWh[buf], sWl[buf], wm, wn, ln, qd, accH, accL);
    }

    const int gnl = wn * 16 + ln;
    const int gn = n0 + gnl;
    #pragma unroll
    for (int ms = 0; ms < 2; ++ms) {
        #pragma unroll
        for (int r = 0; r < 4; ++r) {
            const int m = m0 + wm * 32 + ms * 16 + qd * 4 + r;
            const float gR = sBi[0][gnl] + sBh[0][gnl] + accH[0][ms][r] + accL[0][ms][r] * INV_LO;
            const float gZ = sBi[1][gnl] + sBh[1][gnl] + accH[1][ms][r] + accL[1][ms][r] * INV_LO;
            const float gNi = sBi[2][gnl] + accH[2][ms][r] + accL[2][ms][r] * INV_LO;
            const float gNh = sBh[2][gnl] + accH[3][ms][r] + accL[3][ms][r] * INV_LO;
            const float R = sigmoidf_(gR), Z = sigmoidf_(gZ);
            const float N = tanhf(fmaf(R, gNh, gNi));
            const size_t idx = hidx(m, gn);
            const float hp = (float)Ahh[idx] + (float)Ahl[idx] * INV_LO;
            const float hv = (1.f - Z) * N + Z * hp;
            split_f16(hv, &hnh[idx], &hnl[idx]);
        }
    }
}

// ---------------- final-step output projection (baseline) ----------------
__global__ __launch_bounds__(256) void yout_final_kernel(
    const _Float16* __restrict__ h2h, const _Float16* __restrict__ h2l,
    const float* __restrict__ Wout, const float* __restrict__ bout,
    float* __restrict__ out)
{
    const int wv = threadIdx.x >> 6, lane = threadIdx.x & 63;
    const int b = blockIdx.x * 4 + wv;
    const size_t hb = (size_t)b * H + lane * 8;
    half8 hh = *(const half8*)(h2h + hb);
    half8 hl = *(const half8*)(h2l + hb);
    const int tl = lane >> 3, cw = lane & 7;
    const int kbase = tl * 64 + ((cw ^ (b & 7)) << 3);
    float hv[8];
    #pragma unroll
    for (int j = 0; j < 8; ++j) hv[j] = (float)hh[j] + (float)hl[j] * INV_LO;
    float acc[NO];
    #pragma unroll
    for (int o = 0; o < NO; ++o) {
        acc[o] = 0.f;
        const float* w = Wout + (size_t)o * H + kbase;
        #pragma unroll
        for (int j = 0; j < 8; ++j) acc[o] = fmaf(hv[j], w[j], acc[o]);
    }
    #pragma unroll
    for (int off = 32; off > 0; off >>= 1)
        #pragma unroll
        for (int o = 0; o < NO; ++o) acc[o] += __shfl_down(acc[o], off, 64);
    if (lane == 0) {
        #pragma unroll
        for (int o = 0; o < NO; ++o)
            out[(size_t)b * (T * NO) + (size_t)(T - 1) * NO + o] = acc[o] + bout[o];
    }
}

extern "C" void kernel_launch(void* const* d_in, const int* in_sizes, int n_in,
                              void* d_out, int out_size, void* d_ws, size_t ws_size,
                              hipStream_t stream) {
    (void)in_sizes; (void)n_in; (void)out_size; (void)ws_size;
    const float* cmds  = (const float*)d_in[1];
    const float* y0    = (const float*)d_in[2];
    const float* h01   = (const float*)d_in[3];
    const float* h02   = (const float*)d_in[4];
    const float* W_ih1 = (const float*)d_in[5];
    const float* W_hh1 = (const float*)d_in[6];
    const float* b_ih1 = (const float*)d_in[7];
    const float* b_hh1 = (const float*)d_in[8];
    const float* W_ih2 = (const float*)d_in[9];
    const float* W_hh2 = (const float*)d_in[10];
    const float* b_ih2 = (const float*)d_in[11];
    const float* b_hh2 = (const float*)d_in[12];
    const float* W_out = (const float*)d_in[13];
    const float* b_out = (const float*)d_in[14];
    float* out = (float*)d_out;

    // ---- workspace (~25.5 MB) ----
    char* ws = (char*)d_ws;
    size_t o = 0;
    const size_t WSZ = (size_t)G3H * H * sizeof(_Float16);
    _Float16* wh1h = (_Float16*)(ws + o); o += WSZ;
    _Float16* wh1l = (_Float16*)(ws + o); o += WSZ;
    _Float16* wi2h = (_Float16*)(ws + o); o += WSZ;
    _Float16* wi2l = (_Float16*)(ws + o); o += WSZ;
    _Float16* wh2h = (_Float16*)(ws + o); o += WSZ;
    _Float16* wh2l = (_Float16*)(ws + o); o += WSZ;
    _Float16 *h1h[2], *h1l[2], *h2h[2], *h2l[2];
    for (int i = 0; i < 2; ++i) { h1h[i] = (_Float16*)(ws + o); o += BHE * 2; }
    for (int i = 0; i < 2; ++i) { h1l[i] = (_Float16*)(ws + o); o += BHE * 2; }
    for (int i = 0; i < 2; ++i) { h2h[i] = (_Float16*)(ws + o); o += BHE * 2; }
    for (int i = 0; i < 2; ++i) { h2l[i] = (_Float16*)(ws + o); o += BHE * 2; }

    conv3_kernel<<<(G3H * H + 255) / 256, 256, 0, stream>>>(
        W_hh1, W_ih2, W_hh2, wh1h, wh1l, wi2h, wi2l, wh2h, wh2l);
    prep_kernel<<<(B * H + 255) / 256, 256, 0, stream>>>(
        h01, h02, h1h[0], h1l[0], h2h[0], h2l[0]);

    for (int t = 0; t < T; ++t) {
        const int si = t & 1, so = si ^ 1;

        gru1_kernel<<<256, 512, 0, stream>>>(
            h1h[si], h1l[si], wh1h, wh1l,
            h2h[si], h2l[si], W_out, b_out,
            y0, cmds + (size_t)t * B * NC,
            W_ih1, b_ih1, b_hh1,
            h1h[so], h1l[so],
            out, t);

        gru2_kernel<<<256, 512, 0, stream>>>(
            h1h[so], h1l[so], wi2h, wi2l,
            h2h[si], h2l[si], wh2h, wh2l,
            b_ih2, b_hh2,
            h2h[so], h2l[so]);
    }

    // final y_{T-1}: T even -> final h2 in slot 0
    yout_final_kernel<<<B / 4, 256, 0, stream>>>(
        h2h[0], h2l[0], W_out, b_out, out);
}

// Round 7
// 8191.737 us; speedup vs baseline: 2.3468x; 1.1071x over previous
//
#include <hip/hip_runtime.h>
#include <math.h>

// Problem constants
#define B 2048
#define T 128
#define H 512
#define NC 3
#define NO 5
#define G3H 1536
#define BHE ((size_t)B * H)

typedef _Float16 half8 __attribute__((ext_vector_type(8)));
typedef float float4v __attribute__((ext_vector_type(4)));

#define LO_SCALE 1024.0f
#define INV_LO (1.0f / 1024.0f)
#define F16_MIN_NORM 6.103515625e-05f

__device__ __forceinline__ float sigmoidf_(float x) { return 1.0f / (1.0f + __expf(-x)); }

// Split fp32 -> (hi, lo*1024) f16 pair; hi zeroed in subnormal range (flush safety).
__device__ __forceinline__ void split_f16(float a, _Float16* hi, _Float16* lo) {
    _Float16 h = (_Float16)a;
    if (fabsf(a) < F16_MIN_NORM) h = (_Float16)0.0f;
    *hi = h;
    *lo = (_Float16)((a - (float)h) * LO_SCALE);
}

// element (row,k) of a 512-col matrix stored at row*512 + swzk(row,k):
// 16B chunk c=(k>>3)&7 lives in slot c ^ (row&7)  (LDS-conflict-free fragments)
__device__ __forceinline__ int swzk(int row, int k) {
    return (k & ~63) | ((((k >> 3) & 7) ^ (row & 7)) << 3) | (k & 7);
}
__device__ __forceinline__ size_t hidx(int row, int k) {
    return (size_t)row * H + swzk(row, k);
}

// async 16B global->LDS (wave-uniform LDS base; lane lands at base + lane*16B)
__device__ __forceinline__ void stage16(const _Float16* gp, _Float16* lp) {
    __builtin_amdgcn_global_load_lds(
        (const __attribute__((address_space(1))) unsigned int*)gp,
        (__attribute__((address_space(3))) unsigned int*)lp,
        16, 0, 0);
}

// ---------------- prep kernels (once per launch) ----------------
__global__ void conv3_kernel(const float* __restrict__ w1, const float* __restrict__ w2,
                             const float* __restrict__ w3,
                             _Float16* o1h, _Float16* o1l, _Float16* o2h, _Float16* o2l,
                             _Float16* o3h, _Float16* o3l) {
    int i = blockIdx.x * 256 + threadIdx.x;
    if (i < G3H * H) {
        const int r = i >> 9, k = i & 511;
        const size_t d = (size_t)r * H + swzk(r, k);
        split_f16(w1[i], &o1h[d], &o1l[d]);
        split_f16(w2[i], &o2h[d], &o2l[d]);
        split_f16(w3[i], &o3h[d], &o3l[d]);
    }
}

__global__ void prep_kernel(const float* __restrict__ h01, const float* __restrict__ h02,
                            _Float16* h1h, _Float16* h1l, _Float16* h2h, _Float16* h2l) {
    int i = blockIdx.x * 256 + threadIdx.x;
    if (i < B * H) {
        const int r = i >> 9, k = i & 511;
        const size_t d = (size_t)r * H + swzk(r, k);
        split_f16(h01[i], &h1h[d], &h1l[d]);
        split_f16(h02[i], &h2h[d], &h2l[d]);
    }
}

// ---------------- staging: one 64x64 K-tile (A 16KB + 3-gate 64-col W 48KB) ----------------
// 512 threads: A = 512 chunks (1/thread/component), W = 1536 chunks (3/thread/comp)
__device__ __forceinline__ void stage_tile(
    const _Float16* __restrict__ Ahp, const _Float16* __restrict__ Alp,
    const _Float16* __restrict__ Whp, const _Float16* __restrict__ Wlp,
    int m0, int n0, int k0, int tid, int wv,
    _Float16* sAh, _Float16* sAl, _Float16* sWh, _Float16* sWl)
{
    {
        const int row = tid >> 3, kc = tid & 7;
        const size_t off = (size_t)(m0 + row) * H + k0 + kc * 8;
        stage16(Ahp + off, &sAh[(wv * 64) * 8]);
        stage16(Alp + off, &sAl[(wv * 64) * 8]);
    }
    #pragma unroll
    for (int j = 0; j < 3; ++j) {
        const int cid = j * 512 + tid;
        const int gg = cid >> 9, rem = cid & 511;
        const int nr = rem >> 3, kc = rem & 7;
        const size_t off = (size_t)(gg * H + n0 + nr) * H + k0 + kc * 8;
        stage16(Whp + off, &sWh[(j * 512 + wv * 64) * 8]);
        stage16(Wlp + off, &sWl[(j * 512 + wv * 64) * 8]);
    }
}

// ---------------- staging: one 64x64 A-tile + 3-gate 32-col W tile (A 16KB + W 24KB) ----------------
// W chunks: 768 per comp (3 gates x 32 rows x 8 kc). Threads 0-511 -> chunks 0-511 (gates 0,1);
// threads 0-255 (waves 0-3, fully active) -> chunks 512-767 (gate 2).
__device__ __forceinline__ void stage_tile32(
    const _Float16* __restrict__ Ahp, const _Float16* __restrict__ Alp,
    const _Float16* __restrict__ Whp, const _Float16* __restrict__ Wlp,
    int m0, int n0, int k0, int tid, int wv,
    _Float16* sAh, _Float16* sAl, _Float16* sWh, _Float16* sWl)
{
    {
        const int row = tid >> 3, kc = tid & 7;
        const size_t off = (size_t)(m0 + row) * H + k0 + kc * 8;
        stage16(Ahp + off, &sAh[(wv * 64) * 8]);
        stage16(Alp + off, &sAl[(wv * 64) * 8]);
    }
    {
        const int g = tid >> 8, rem = tid & 255;     // gates 0,1
        const int nr = rem >> 3, kc = rem & 7;
        const size_t off = (size_t)(g * H + n0 + nr) * H + k0 + kc * 8;
        stage16(Whp + off, &sWh[(wv * 64) * 8]);
        stage16(Wlp + off, &sWl[(wv * 64) * 8]);
    }
    if (tid < 256) {                                  // gate 2
        const int nr = tid >> 3, kc = tid & 7;
        const size_t off = (size_t)(2 * H + n0 + nr) * H + k0 + kc * 8;
        stage16(Whp + off, &sWh[(512 + wv * 64) * 8]);
        stage16(Wlp + off, &sWl[(512 + wv * 64) * 8]);
    }
}

// ---------------- baseline compute tile (wm=wv>>1, wn=wv&1; N=64) ----------------
__device__ __forceinline__ void compute_tile(
    const _Float16* sAh, const _Float16* sAl,
    const _Float16* sWh, const _Float16* sWl,
    int wm, int wn, int ln, int qd, int sN,
    float4v (&accH)[4][2], float4v (&accL)[4][2])
{
    #pragma unroll
    for (int ks = 0; ks < 2; ++ks) {
        const int c = ks * 4 + qd;
        const int row = wm * 16 + ln;
        const int ai = row * 64 + ((c ^ (row & 7)) << 3);
        half8 afh = *(const half8*)&sAh[ai];
        half8 afl = *(const half8*)&sAl[ai];
        #pragma unroll
        for (int g = 0; g < 3; ++g) {
            const int s = (g < 2) ? g : sN;
            #pragma unroll
            for (int nt = 0; nt < 2; ++nt) {
                const int nr = wn * 32 + nt * 16 + ln;
                const int wi = (g * 64 + nr) * 64 + ((c ^ (nr & 7)) << 3);
                half8 bh = *(const half8*)&sWh[wi];
                half8 bl = *(const half8*)&sWl[wi];
                accH[s][nt] = __builtin_amdgcn_mfma_f32_16x16x32_f16(afh, bh, accH[s][nt], 0, 0, 0);
                accL[s][nt] = __builtin_amdgcn_mfma_f32_16x16x32_f16(afh, bl, accL[s][nt], 0, 0, 0);
                accL[s][nt] = __builtin_amdgcn_mfma_f32_16x16x32_f16(afl, bh, accL[s][nt], 0, 0, 0);
            }
        }
    }
}

// ---------------- N=32 compute tile (wave: 16 rows x 16 cols x 3 gates) ----------------
template <int SN>
__device__ __forceinline__ void compute_tile32(
    const _Float16* sAh_, const _Float16* sAl_,
    const _Float16* sWh_, const _Float16* sWl_,
    int wm, int wn, int ln, int qd,
    float4v (&accH)[4], float4v (&accL)[4])
{
    #pragma unroll
    for (int ks = 0; ks < 2; ++ks) {
        const int c = ks * 4 + qd;
        const int row = wm * 16 + ln;
        const int ai = row * 64 + ((c ^ (row & 7)) << 3);
        half8 afh = *(const half8*)&sAh_[ai];
        half8 afl = *(const half8*)&sAl_[ai];
        const int nr = wn * 16 + ln;
        #pragma unroll
        for (int g = 0; g < 3; ++g) {
            const int s = (g < 2) ? g : SN;
            const int wi = (g * 32 + nr) * 64 + ((c ^ (nr & 7)) << 3);
            half8 bh = *(const half8*)&sWh_[wi];
            half8 bl = *(const half8*)&sWl_[wi];
            accH[s] = __builtin_amdgcn_mfma_f32_16x16x32_f16(afh, bh, accH[s], 0, 0, 0);
            accL[s] = __builtin_amdgcn_mfma_f32_16x16x32_f16(afh, bl, accL[s], 0, 0, 0);
            accL[s] = __builtin_amdgcn_mfma_f32_16x16x32_f16(afl, bh, accL[s], 0, 0, 0);
        }
    }
}

// ---------------- layer-1 GRU step (+ fused y_{t-1} projection) — round-0 baseline ----------------
__global__ __launch_bounds__(512, 1) void gru1_kernel(
    const _Float16* __restrict__ Ah, const _Float16* __restrict__ Al,    // h1 prev swz
    const _Float16* __restrict__ Wh, const _Float16* __restrict__ Wl,    // wh1 swz
    const _Float16* __restrict__ h2ph, const _Float16* __restrict__ h2pl,// h2 prev swz
    const float* __restrict__ Wout, const float* __restrict__ bout,
    const float* __restrict__ y0, const float* __restrict__ cmd_t,
    const float* __restrict__ W_ih1,
    const float* __restrict__ b_ih1, const float* __restrict__ b_hh1,
    _Float16* __restrict__ hnh, _Float16* __restrict__ hnl,
    float* __restrict__ out, int t)
{
    __shared__ _Float16 sAh[2][4096], sAl[2][4096];     // 32 KB
    __shared__ _Float16 sWh[2][12288], sWl[2][12288];   // 96 KB
    __shared__ float sX[64 * 8];
    __shared__ float sWi1[3][8][64];
    __shared__ float sBi1[3][64], sBh1[3][64];

    const int tid = threadIdx.x;
    const int wv = tid >> 6, lane = tid & 63;
    const int wm = wv >> 1, wn = wv & 1;
    const int ln = lane & 15, qd = lane >> 4;
    const int n0 = (blockIdx.x & 7) * 64;
    const int m0 = (blockIdx.x >> 3) * 64;

    // one-time LDS fills (consumed after K-loop syncs)
    for (int i = tid; i < 3 * 64 * 8; i += 512) {
        const int g = i >> 9, rem = i & 511, n = rem >> 3, k = rem & 7;
        sWi1[g][k][n] = W_ih1[(g * H + n0 + n) * 8 + k];
    }
    if (tid < 192) {
        const int g = tid >> 6, n = tid & 63;
        sBi1[g][n] = b_ih1[g * H + n0 + n];
        sBh1[g][n] = b_hh1[g * H + n0 + n];
    }

    float4v accH[4][2], accL[4][2];
    #pragma unroll
    for (int s = 0; s < 4; ++s)
        #pragma unroll
        for (int nt = 0; nt < 2; ++nt) { accH[s][nt] = (float4v)(0.f); accL[s][nt] = (float4v)(0.f); }

    // kick off tile 0 (async), then overlap the y-projection with its flight
    stage_tile(Ah, Al, Wh, Wl, m0, n0, 0, tid, wv, sAh[0], sAl[0], sWh[0], sWl[0]);

    // ---- y_{t-1} = h2_prev . Wout^T + bout (this block's 64 rows) ----
    const int yr = tid >> 3, yp = tid & 7;   // row, K-octant
    if (t == 0) {
        if (tid < 64) {
            #pragma unroll
            for (int o2 = 0; o2 < NO; ++o2)
                sX[tid * 8 + o2] = y0[(size_t)(m0 + tid) * NO + o2];
        }
    } else {
        const int row = m0 + yr;
        float a5[NO] = {0.f, 0.f, 0.f, 0.f, 0.f};
        #pragma unroll
        for (int s = 0; s < 8; ++s) {
            const size_t base = (size_t)row * H + yp * 64 + s * 8;
            half8 hh8 = *(const half8*)(h2ph + base);
            half8 hl8 = *(const half8*)(h2pl + base);
            const int kb = yp * 64 + ((s ^ (row & 7)) << 3);
            #pragma unroll
            for (int j4 = 0; j4 < 2; ++j4) {
                float4 wv4[NO];
                #pragma unroll
                for (int o2 = 0; o2 < NO; ++o2)
                    wv4[o2] = *(const float4*)(Wout + (size_t)o2 * H + kb + j4 * 4);
                #pragma unroll
                for (int jj = 0; jj < 4; ++jj) {
                    const int j = j4 * 4 + jj;
                    const float hv = (float)hh8[j] + (float)hl8[j] * INV_LO;
                    a5[0] = fmaf(hv, ((const float*)&wv4[0])[jj], a5[0]);
                    a5[1] = fmaf(hv, ((const float*)&wv4[1])[jj], a5[1]);
                    a5[2] = fmaf(hv, ((const float*)&wv4[2])[jj], a5[2]);
                    a5[3] = fmaf(hv, ((const float*)&wv4[3])[jj], a5[3]);
                    a5[4] = fmaf(hv, ((const float*)&wv4[4])[jj], a5[4]);
                }
            }
        }
        #pragma unroll
        for (int off = 1; off < 8; off <<= 1)
            #pragma unroll
            for (int o2 = 0; o2 < NO; ++o2) a5[o2] += __shfl_xor(a5[o2], off, 64);
        if (yp == 0) {
            #pragma unroll
            for (int o2 = 0; o2 < NO; ++o2) {
                const float y = a5[o2] + bout[o2];
                sX[yr * 8 + o2] = y;
                if (n0 == 0)
                    out[(size_t)(m0 + yr) * (T * NO) + (size_t)(t - 1) * NO + o2] = y;
            }
        }
    }
    if (tid < 64) {
        #pragma unroll
        for (int c = 0; c < NC; ++c)
            sX[tid * 8 + NO + c] = cmd_t[(size_t)(m0 + tid) * NC + c];
    }

    // ---- K-loop: gh = h1_prev @ W_hh1^T (8 tiles), n-gate -> set 3 ----
    for (int it = 0; it < 8; ++it) {
        const int buf = it & 1;
        __syncthreads();
        if (it + 1 < 8)
            stage_tile(Ah, Al, Wh, Wl, m0, n0, (it + 1) * 64, tid, wv,
                       sAh[buf ^ 1], sAl[buf ^ 1], sWh[buf ^ 1], sWl[buf ^ 1]);
        compute_tile(sAh[buf], sAl[buf], sWh[buf], sWl[buf], wm, wn, ln, qd, 3, accH, accL);
    }

    // ---- epilogue: fp32 input path (K=8) + gates + blend ----
    #pragma unroll
    for (int nt = 0; nt < 2; ++nt) {
        const int gnl = wn * 32 + nt * 16 + ln;
        const int gn = n0 + gnl;
        #pragma unroll
        for (int r = 0; r < 4; ++r) {
            const int mloc = wm * 16 + qd * 4 + r;
            const int m = m0 + mloc;
            float giR = sBi1[0][gnl], giZ = sBi1[1][gnl], giN = sBi1[2][gnl];
            #pragma unroll
            for (int k = 0; k < 8; ++k) {
                const float xv = sX[mloc * 8 + k];
                giR = fmaf(xv, sWi1[0][k][gnl], giR);
                giZ = fmaf(xv, sWi1[1][k][gnl], giZ);
                giN = fmaf(xv, sWi1[2][k][gnl], giN);
            }
            const float gR = giR + sBh1[0][gnl] + accH[0][nt][r] + accL[0][nt][r] * INV_LO;
            const float gZ = giZ + sBh1[1][gnl] + accH[1][nt][r] + accL[1][nt][r] * INV_LO;
            const float gNh = sBh1[2][gnl] + accH[3][nt][r] + accL[3][nt][r] * INV_LO;
            const float R = sigmoidf_(gR), Z = sigmoidf_(gZ);
            const float N = tanhf(fmaf(R, gNh, giN));
            const size_t idx = hidx(m, gn);
            const float hp = (float)Ah[idx] + (float)Al[idx] * INV_LO;
            const float hv = (1.f - Z) * N + Z * hp;
            split_f16(hv, &hnh[idx], &hnl[idx]);
        }
    }
}

// ---------------- layer-2 GRU step — N=32 tile, exactly 80KB LDS -> 2 blocks/CU ----------------
__global__ __launch_bounds__(512, 4) void gru2_kernel(
    const _Float16* __restrict__ Aih, const _Float16* __restrict__ Ail,  // h1 cur swz
    const _Float16* __restrict__ Wih, const _Float16* __restrict__ Wil,  // wi2 swz
    const _Float16* __restrict__ Ahh, const _Float16* __restrict__ Ahl,  // h2 prev swz
    const _Float16* __restrict__ Whh, const _Float16* __restrict__ Whl,  // wh2 swz
    const float* __restrict__ b_i, const float* __restrict__ b_h,
    _Float16* __restrict__ hnh, _Float16* __restrict__ hnl)
{
    __shared__ _Float16 sAh[2][4096], sAl[2][4096];   // 64x64 A (16KB + 16KB)
    __shared__ _Float16 sWh[2][6144], sWl[2][6144];   // 3x32x64 W (24KB + 24KB) => 80KB total

    const int tid = threadIdx.x;
    const int wv = tid >> 6, lane = tid & 63;
    const int wm = wv >> 1, wn = wv & 1;
    const int ln = lane & 15, qd = lane >> 4;
    const int n0 = (blockIdx.x & 15) * 32;            // 16 n-groups of 32 cols
    const int m0 = (blockIdx.x >> 4) * 64;

    float4v accH[4], accL[4];
    #pragma unroll
    for (int s = 0; s < 4; ++s) { accH[s] = (float4v)(0.f); accL[s] = (float4v)(0.f); }

    stage_tile32(Aih, Ail, Wih, Wil, m0, n0, 0, tid, wv, sAh[0], sAl[0], sWh[0], sWl[0]);
    for (int it = 0; it < 16; ++it) {
        const int buf = it & 1;
        __syncthreads();
        if (it + 1 < 16) {
            const int k0 = ((it + 1) & 7) * 64;
            if (it + 1 < 8)
                stage_tile32(Aih, Ail, Wih, Wil, m0, n0, k0, tid, wv,
                             sAh[buf ^ 1], sAl[buf ^ 1], sWh[buf ^ 1], sWl[buf ^ 1]);
            else
                stage_tile32(Ahh, Ahl, Whh, Whl, m0, n0, k0, tid, wv,
                             sAh[buf ^ 1], sAl[buf ^ 1], sWh[buf ^ 1], sWl[buf ^ 1]);
        }
        if (it < 8)
            compute_tile32<2>(sAh[buf], sAl[buf], sWh[buf], sWl[buf], wm, wn, ln, qd, accH, accL);
        else
            compute_tile32<3>(sAh[buf], sAl[buf], sWh[buf], sWl[buf], wm, wn, ln, qd, accH, accL);
    }

    // epilogue: biases read directly from global (L2-resident; keeps LDS at exactly 80KB)
    const int gnl = wn * 16 + ln;
    const int gn = n0 + gnl;
    const float bi0 = b_i[0 * H + gn], bi1 = b_i[1 * H + gn], bi2 = b_i[2 * H + gn];
    const float bh0 = b_h[0 * H + gn], bh1 = b_h[1 * H + gn], bh2 = b_h[2 * H + gn];
    #pragma unroll
    for (int r = 0; r < 4; ++r) {
        const int m = m0 + wm * 16 + qd * 4 + r;
        const float gR = bi0 + bh0 + accH[0][r] + accL[0][r] * INV_LO;
        const float gZ = bi1 + bh1 + accH[1][r] + accL[1][r] * INV_LO;
        const float gNi = bi2 + accH[2][r] + accL[2][r] * INV_LO;
        const float gNh = bh2 + accH[3][r] + accL[3][r] * INV_LO;
        const float R = sigmoidf_(gR), Z = sigmoidf_(gZ);
        const float N = tanhf(fmaf(R, gNh, gNi));
        const size_t idx = hidx(m, gn);
        const float hp = (float)Ahh[idx] + (float)Ahl[idx] * INV_LO;
        const float hv = (1.f - Z) * N + Z * hp;
        split_f16(hv, &hnh[idx], &hnl[idx]);
    }
}

// ---------------- final-step output projection (baseline) ----------------
__global__ __launch_bounds__(256) void yout_final_kernel(
    const _Float16* __restrict__ h2h, const _Float16* __restrict__ h2l,
    const float* __restrict__ Wout, const float* __restrict__ bout,
    float* __restrict__ out)
{
    const int wv = threadIdx.x >> 6, lane = threadIdx.x & 63;
    const int b = blockIdx.x * 4 + wv;
    const size_t hb = (size_t)b * H + lane * 8;
    half8 hh = *(const half8*)(h2h + hb);
    half8 hl = *(const half8*)(h2l + hb);
    const int tl = lane >> 3, cw = lane & 7;
    const int kbase = tl * 64 + ((cw ^ (b & 7)) << 3);
    float hv[8];
    #pragma unroll
    for (int j = 0; j < 8; ++j) hv[j] = (float)hh[j] + (float)hl[j] * INV_LO;
    float acc[NO];
    #pragma unroll
    for (int o = 0; o < NO; ++o) {
        acc[o] = 0.f;
        const float* w = Wout + (size_t)o * H + kbase;
        #pragma unroll
        for (int j = 0; j < 8; ++j) acc[o] = fmaf(hv[j], w[j], acc[o]);
    }
    #pragma unroll
    for (int off = 32; off > 0; off >>= 1)
        #pragma unroll
        for (int o = 0; o < NO; ++o) acc[o] += __shfl_down(acc[o], off, 64);
    if (lane == 0) {
        #pragma unroll
        for (int o = 0; o < NO; ++o)
            out[(size_t)b * (T * NO) + (size_t)(T - 1) * NO + o] = acc[o] + bout[o];
    }
}

extern "C" void kernel_launch(void* const* d_in, const int* in_sizes, int n_in,
                              void* d_out, int out_size, void* d_ws, size_t ws_size,
                              hipStream_t stream) {
    (void)in_sizes; (void)n_in; (void)out_size; (void)ws_size;
    const float* cmds  = (const float*)d_in[1];
    const float* y0    = (const float*)d_in[2];
    const float* h01   = (const float*)d_in[3];
    const float* h02   = (const float*)d_in[4];
    const float* W_ih1 = (const float*)d_in[5];
    const float* W_hh1 = (const float*)d_in[6];
    const float* b_ih1 = (const float*)d_in[7];
    const float* b_hh1 = (const float*)d_in[8];
    const float* W_ih2 = (const float*)d_in[9];
    const float* W_hh2 = (const float*)d_in[10];
    const float* b_ih2 = (const float*)d_in[11];
    const float* b_hh2 = (const float*)d_in[12];
    const float* W_out = (const float*)d_in[13];
    const float* b_out = (const float*)d_in[14];
    float* out = (float*)d_out;

    // ---- workspace (~25.5 MB) ----
    char* ws = (char*)d_ws;
    size_t o = 0;
    const size_t WSZ = (size_t)G3H * H * sizeof(_Float16);
    _Float16* wh1h = (_Float16*)(ws + o); o += WSZ;
    _Float16* wh1l = (_Float16*)(ws + o); o += WSZ;
    _Float16* wi2h = (_Float16*)(ws + o); o += WSZ;
    _Float16* wi2l = (_Float16*)(ws + o); o += WSZ;
    _Float16* wh2h = (_Float16*)(ws + o); o += WSZ;
    _Float16* wh2l = (_Float16*)(ws + o); o += WSZ;
    _Float16 *h1h[2], *h1l[2], *h2h[2], *h2l[2];
    for (int i = 0; i < 2; ++i) { h1h[i] = (_Float16*)(ws + o); o += BHE * 2; }
    for (int i = 0; i < 2; ++i) { h1l[i] = (_Float16*)(ws + o); o += BHE * 2; }
    for (int i = 0; i < 2; ++i) { h2h[i] = (_Float16*)(ws + o); o += BHE * 2; }
    for (int i = 0; i < 2; ++i) { h2l[i] = (_Float16*)(ws + o); o += BHE * 2; }

    conv3_kernel<<<(G3H * H + 255) / 256, 256, 0, stream>>>(
        W_hh1, W_ih2, W_hh2, wh1h, wh1l, wi2h, wi2l, wh2h, wh2l);
    prep_kernel<<<(B * H + 255) / 256, 256, 0, stream>>>(
        h01, h02, h1h[0], h1l[0], h2h[0], h2l[0]);

    for (int t = 0; t < T; ++t) {
        const int si = t & 1, so = si ^ 1;

        gru1_kernel<<<256, 512, 0, stream>>>(
            h1h[si], h1l[si], wh1h, wh1l,
            h2h[si], h2l[si], W_out, b_out,
            y0, cmds + (size_t)t * B * NC,
            W_ih1, b_ih1, b_hh1,
            h1h[so], h1l[so],
            out, t);

        gru2_kernel<<<512, 512, 0, stream>>>(
            h1h[so], h1l[so], wi2h, wi2l,
            h2h[si], h2l[si], wh2h, wh2l,
            b_ih2, b_hh2,
            h2h[so], h2l[so]);
    }

    // final y_{T-1}: T even -> final h2 in slot 0
    yout_final_kernel<<<B / 4, 256, 0, stream>>>(
        h2h[0], h2l[0], W_out, b_out, out);
}